// Round 2
// baseline (3017.540 us; speedup 1.0000x reference)
//
#include <hip/hip_runtime.h>
#include <hip/hip_bf16.h>

// GCN 3-layer: gcn_norm -> (GCNConv, ELU) x2 -> GCNConv
// N=100000, E=3200000, dims 128->32->64->128.
// agg is linear => aggregate in the SMALLER feature dim per layer:
//   L1: t1 = x@W1 (128->32); a1 = ELU(agg(t1) + b1)          [gather F=32]
//   L2: s2 = agg(a1);        h2 = ELU(s2@W2 + b2)            [gather F=32]
//   L3: s3 = agg(h2);        out = s3@W3 + b3                [gather F=64]
//
// CSR/bucket build: bucketed 2-level counting sort (round 1):
//   k_hist -> k_bscan -> k_scatter produce tmp[] = edges sorted by
//   128-node target bucket, entry (r | c7<<17, w).
// Round 2 rework: the node-parallel CSR agg was LATENCY-bound (45% BW,
// VALU 12%): each 16-lane node group could only keep ~4 gathers in
// flight (accumulate needs vmcnt drain). Replaced with EDGE-PARALLEL
// aggregation straight from tmp[]: one bucket per 512-thread block,
// acc[128][F] in LDS (row stride F+4 pads rotate banks per target),
// edges processed independently (unroll x4) with ds_add_f32 -- no
// loop-carried dep, so gathers pipeline deeply. This also deletes
// epk/k_fill2 and the per-node offsets/counts entirely; dinv[src]*ew
// is applied on the fly (dinv is 400KB, L2-resident).
// GEMMs register-blocked 64-row tiles. Inputs: fp32 (probed vs bf16),
// edge_index i64 (probed vs i32). Output fp32.

constexpr int N = 100000;
constexpr int E = 3200000;

constexpr int BSHIFT = 7;
constexpr int BSIZE = 128;                       // nodes per bucket
constexpr int NBKT = (N + BSIZE - 1) / BSIZE;    // 782

constexpr float FIX_SCALE = 16777216.0f;         // 2^24

constexpr int HIST_EPB = 8192;                   // edges per block, hist
constexpr int SC_EPB = 16384;                    // edges per block, scatter

__device__ __forceinline__ float ldf(const void* p, int isbf, size_t i) {
    return isbf ? __bfloat162float(((const __hip_bfloat16*)p)[i])
                : ((const float*)p)[i];
}

__device__ __forceinline__ int ld_idx(const void* ei, int is64, size_t pos) {
    return is64 ? (int)((const long long*)ei)[pos] : ((const int*)ei)[pos];
}

// flags[0] = is64 (edge_index), flags[1] = isbf (float tensors)
// also zeroes the bucket-count array (runs before k_hist on the stream)
__global__ void k_probe(const void* ei, const void* x, int* flags, int* bkt_cnt) {
    __shared__ int bad64, bigcnt;
    int t = threadIdx.x;
    if (t == 0) { bad64 = 0; bigcnt = 0; }
    __syncthreads();
    long long v = ((const long long*)ei)[t];
    if (v < 0 || v >= (long long)N) atomicAdd(&bad64, 1);
    const unsigned short* u = (const unsigned short*)x;
    int big = 0;
    for (int i = t * 16; i < t * 16 + 16; i++) {
        int e = (u[i] >> 7) & 0xFF;
        if (e >= 133) big++;
    }
    atomicAdd(&bigcnt, big);
    for (int i = t; i < NBKT; i += 256) bkt_cnt[i] = 0;
    __syncthreads();
    if (t == 0) { flags[0] = (bad64 == 0) ? 1 : 0; flags[1] = (bigcnt < 40) ? 1 : 0; }
}

// bucket histogram: LDS per block, one global atomic per (block,bucket)
__global__ __launch_bounds__(256) void k_hist(const void* ei, const int* flags,
                                              int* bkt_cnt) {
    __shared__ int h[NBKT];
    int t = threadIdx.x;
    for (int i = t; i < NBKT; i += 256) h[i] = 0;
    __syncthreads();
    int is64 = flags[0];
    size_t eb = (size_t)blockIdx.x * HIST_EPB;
#pragma unroll 4
    for (int k = 0; k < HIST_EPB / 256; k++) {
        size_t e = eb + t + (size_t)k * 256;
        if (e < (size_t)E) {
            int c = ld_idx(ei, is64, (size_t)E + e);
            atomicAdd(&h[c >> BSHIFT], 1);
        }
    }
    __syncthreads();
    for (int i = t; i < NBKT; i += 256) {
        int v = h[i];
        if (v) atomicAdd(&bkt_cnt[i], v);
    }
}

// single-block exclusive scan over NBKT buckets -> bkt_off, bkt_cur
__global__ void k_bscan(const int* bkt_cnt, int* bkt_off, int* bkt_cur) {
    __shared__ int s[256];
    int t = threadIdx.x;
    int v[4]; int sum = 0;
#pragma unroll
    for (int j = 0; j < 4; j++) {
        int i = t * 4 + j;
        v[j] = (i < NBKT) ? bkt_cnt[i] : 0;
        sum += v[j];
    }
    s[t] = sum; __syncthreads();
    for (int st = 1; st < 256; st <<= 1) {
        int add = (t >= st) ? s[t - st] : 0;
        __syncthreads();
        s[t] += add;
        __syncthreads();
    }
    int excl = s[t] - sum;
#pragma unroll
    for (int j = 0; j < 4; j++) {
        int i = t * 4 + j;
        if (i < NBKT) { bkt_off[i] = excl; bkt_cur[i] = excl; excl += v[j]; }
    }
    if (t == 0) bkt_off[NBKT] = E;
}

// bucket-sort edges into tmp[]: per-block LDS histogram, one run
// reservation atomic per (block,bucket), dense run writes.
// tmp entry: .x = r | (c&127)<<17  (r<2^17, fits), .y = w bits
__global__ __launch_bounds__(256) void k_scatter(const void* ei, const int* flags,
                                                 const void* ew, int* bkt_cur,
                                                 int2* tmp) {
    __shared__ int h[NBKT];
    __shared__ int base_s[NBKT];
    int t = threadIdx.x;
    for (int i = t; i < NBKT; i += 256) h[i] = 0;
    __syncthreads();
    int is64 = flags[0], isbf = flags[1];
    size_t eb = (size_t)blockIdx.x * SC_EPB;
    int nb = (int)min((size_t)SC_EPB, (size_t)E - eb);
    // pass 1: local histogram
    for (int k = t; k < nb; k += 256) {
        int c = ld_idx(ei, is64, (size_t)E + eb + k);
        atomicAdd(&h[c >> BSHIFT], 1);
    }
    __syncthreads();
    // reserve a dense run per bucket
    for (int i = t; i < NBKT; i += 256) {
        int v = h[i];
        base_s[i] = v ? atomicAdd(&bkt_cur[i], v) : 0;
    }
    __syncthreads();
    for (int i = t; i < NBKT; i += 256) h[i] = 0;
    __syncthreads();
    // pass 2: place edges within reserved runs
    for (int k = t; k < nb; k += 256) {
        size_t e = eb + k;
        int r = ld_idx(ei, is64, e);
        int c = ld_idx(ei, is64, (size_t)E + e);
        float w = ldf(ew, isbf, e);
        int b = c >> BSHIFT;
        int loc = atomicAdd(&h[b], 1);
        int pos = base_s[b] + loc;
        tmp[pos] = make_int2(r | ((c & (BSIZE - 1)) << 17), __float_as_int(w));
    }
}

// per bucket: fixed-point weight sums (LDS atomics) -> dinv
// dinv = rsqrt(1 + wsum)  (bit-identical to the old packed-atomic scheme)
__global__ __launch_bounds__(256) void k_dinv2(const int2* __restrict__ tmp,
                                               const int* __restrict__ bkt_off,
                                               float* __restrict__ dinv) {
    __shared__ unsigned int wfx_s[BSIZE];
    int t = threadIdx.x;
    int b = blockIdx.x;
    if (t < BSIZE) wfx_s[t] = 0u;
    __syncthreads();
    int s0 = bkt_off[b], s1 = bkt_off[b + 1];
    for (int p = s0 + t; p < s1; p += 256) {
        int2 ev = tmp[p];
        int c7 = (int)(((unsigned)ev.x) >> 17);
        float w = __int_as_float(ev.y);
        atomicAdd(&wfx_s[c7], (unsigned)__float2uint_rn(w * FIX_SCALE));
    }
    __syncthreads();
    if (t < BSIZE) {
        int node = b * BSIZE + t;
        if (node < N) {
            float deg = 1.0f + (float)wfx_s[t] * (1.0f / FIX_SCALE);
            dinv[node] = rsqrtf(deg);
        }
    }
}

// --- edge-parallel bucket aggregation with LDS accumulators
// out[n] = di * Σ_e (dinv[src]*ew_e) * H[src_e] + di^2 * H[n] (+b, ELU)
// One bucket (128 targets) per 512-thread block. acc row stride F+4
// rotates the bank mapping per target row (4-bank shift / row).
template <int F, bool BIAS, bool ELU>
__global__ __launch_bounds__(512) void k_aggb(const float4* __restrict__ H4,
                                              const int2* __restrict__ tmp,
                                              const int* __restrict__ bkt_off,
                                              const float* __restrict__ dinv,
                                              const void* __restrict__ bias,
                                              const int* __restrict__ flags,
                                              float4* __restrict__ out4) {
    constexpr int LPN = F / 4;           // lanes per edge-slot
    constexpr int SLOTS = 512 / LPN;     // 32 (F=64) / 64 (F=32)
    constexpr int RSTR = F + 4;          // padded row stride (floats, 16B-mult)
    __shared__ float acc[BSIZE * RSTR];  // 34.8KB (F=64) / 18.4KB (F=32)
    int t = threadIdx.x;
    int b = blockIdx.x;
    for (int i = t; i < BSIZE * RSTR; i += 512) acc[i] = 0.f;
    __syncthreads();
    int lane = t % LPN;
    int slot = t / LPN;
    int s0 = bkt_off[b], s1 = bkt_off[b + 1];
    int p = s0 + slot;
    // main loop: 4 independent edges per slot in flight
    for (; p + 3 * SLOTS < s1; p += 4 * SLOTS) {
        int2 e0 = tmp[p];
        int2 e1 = tmp[p + SLOTS];
        int2 e2 = tmp[p + 2 * SLOTS];
        int2 e3 = tmp[p + 3 * SLOTS];
        unsigned x0 = (unsigned)e0.x, x1 = (unsigned)e1.x;
        unsigned x2 = (unsigned)e2.x, x3 = (unsigned)e3.x;
        int r0 = (int)(x0 & 0x1FFFFu), r1 = (int)(x1 & 0x1FFFFu);
        int r2 = (int)(x2 & 0x1FFFFu), r3 = (int)(x3 & 0x1FFFFu);
        float4 g0 = H4[(size_t)r0 * LPN + lane];
        float4 g1 = H4[(size_t)r1 * LPN + lane];
        float4 g2 = H4[(size_t)r2 * LPN + lane];
        float4 g3 = H4[(size_t)r3 * LPN + lane];
        float n0 = dinv[r0] * __int_as_float(e0.y);
        float n1 = dinv[r1] * __int_as_float(e1.y);
        float n2 = dinv[r2] * __int_as_float(e2.y);
        float n3 = dinv[r3] * __int_as_float(e3.y);
        float* a0 = &acc[(int)(x0 >> 17) * RSTR + lane * 4];
        float* a1 = &acc[(int)(x1 >> 17) * RSTR + lane * 4];
        float* a2 = &acc[(int)(x2 >> 17) * RSTR + lane * 4];
        float* a3 = &acc[(int)(x3 >> 17) * RSTR + lane * 4];
        atomicAdd(a0 + 0, g0.x * n0); atomicAdd(a0 + 1, g0.y * n0);
        atomicAdd(a0 + 2, g0.z * n0); atomicAdd(a0 + 3, g0.w * n0);
        atomicAdd(a1 + 0, g1.x * n1); atomicAdd(a1 + 1, g1.y * n1);
        atomicAdd(a1 + 2, g1.z * n1); atomicAdd(a1 + 3, g1.w * n1);
        atomicAdd(a2 + 0, g2.x * n2); atomicAdd(a2 + 1, g2.y * n2);
        atomicAdd(a2 + 2, g2.z * n2); atomicAdd(a2 + 3, g2.w * n2);
        atomicAdd(a3 + 0, g3.x * n3); atomicAdd(a3 + 1, g3.y * n3);
        atomicAdd(a3 + 2, g3.z * n3); atomicAdd(a3 + 3, g3.w * n3);
    }
    for (; p < s1; p += SLOTS) {
        int2 ev = tmp[p];
        unsigned px = (unsigned)ev.x;
        int r = (int)(px & 0x1FFFFu);
        float4 g = H4[(size_t)r * LPN + lane];
        float nr = dinv[r] * __int_as_float(ev.y);
        float* a = &acc[(int)(px >> 17) * RSTR + lane * 4];
        atomicAdd(a + 0, g.x * nr); atomicAdd(a + 1, g.y * nr);
        atomicAdd(a + 2, g.z * nr); atomicAdd(a + 3, g.w * nr);
    }
    __syncthreads();
    // epilogue: self-loop + scale + bias + ELU, coalesced write
    int isbf = BIAS ? flags[1] : 0;
    for (int i = t; i < BSIZE * LPN; i += 512) {
        int nl = i / LPN, f4 = i % LPN;
        int node = b * BSIZE + nl;
        if (node >= N) continue;
        float di = dinv[node];
        float sw = di * di;
        float4 h = H4[(size_t)node * LPN + f4];
        float4 a = *(const float4*)&acc[nl * RSTR + f4 * 4];
        a.x = a.x * di + h.x * sw;
        a.y = a.y * di + h.y * sw;
        a.z = a.z * di + h.z * sw;
        a.w = a.w * di + h.w * sw;
        if (BIAS) {
            int fb = f4 * 4;
            a.x += ldf(bias, isbf, fb);
            a.y += ldf(bias, isbf, fb + 1);
            a.z += ldf(bias, isbf, fb + 2);
            a.w += ldf(bias, isbf, fb + 3);
        }
        if (ELU) {
            a.x = (a.x > 0.0f) ? a.x : expm1f(a.x);
            a.y = (a.y > 0.0f) ? a.y : expm1f(a.y);
            a.z = (a.z > 0.0f) ? a.z : expm1f(a.z);
            a.w = (a.w > 0.0f) ? a.w : expm1f(a.w);
        }
        out4[(size_t)node * LPN + f4] = a;
    }
}

// --- register-blocked GEMM: H[N,FOUT] = X[N,FIN] @ W[FIN,FOUT] (+b, ELU)
template <int FIN, int FOUT, int TM, int TN, bool ADAPT, bool BIAS, bool ELU>
__global__ __launch_bounds__(256) void k_gemm(const void* __restrict__ X,
                                              const void* __restrict__ W,
                                              const void* __restrict__ bias,
                                              const int* __restrict__ flags,
                                              float* __restrict__ H) {
    constexpr int TCOLS = FOUT / TN;
    constexpr int TROWS = 256 / TCOLS;
    constexpr int BR = TROWS * TM;
    __shared__ float wl[FIN * FOUT];
    __shared__ float xt[FIN][BR + 1];
    int t = threadIdx.x;
    int isbf = flags[1];
    int base = blockIdx.x * BR;

    if (!isbf) {
        const float4* W4 = (const float4*)W;
        float4* wl4 = (float4*)wl;
        for (int i = t; i < FIN * FOUT / 4; i += 256) wl4[i] = W4[i];
    } else {
        for (int i = t; i < FIN * FOUT; i += 256)
            wl[i] = __bfloat162float(((const __hip_bfloat16*)W)[i]);
    }
    if (!ADAPT || !isbf) {
        const float4* X4 = (const float4*)X;
        for (int i = t; i < BR * FIN / 4; i += 256) {
            int row = i / (FIN / 4);
            int kq = i % (FIN / 4);
            int node = base + row;
            float4 v = make_float4(0.f, 0.f, 0.f, 0.f);
            if (node < N) v = X4[(size_t)node * (FIN / 4) + kq];
            int k = kq * 4;
            xt[k][row] = v.x; xt[k + 1][row] = v.y;
            xt[k + 2][row] = v.z; xt[k + 3][row] = v.w;
        }
    } else {
        for (int i = t; i < BR * FIN; i += 256) {
            int row = i / FIN, k = i % FIN;
            int node = base + row;
            float v = (node < N)
                ? __bfloat162float(((const __hip_bfloat16*)X)[(size_t)node * FIN + k]) : 0.f;
            xt[k][row] = v;
        }
    }
    __syncthreads();

    int tcol = t % TCOLS, trow = t / TCOLS;
    int r0 = trow * TM, c0 = tcol * TN;
    float acc[TM][TN] = {};
#pragma unroll 4
    for (int k = 0; k < FIN; k++) {
        float a[TM], b[TN];
#pragma unroll
        for (int m = 0; m < TM; m++) a[m] = xt[k][r0 + m];
#pragma unroll
        for (int n = 0; n < TN; n++) b[n] = wl[k * FOUT + c0 + n];
#pragma unroll
        for (int m = 0; m < TM; m++)
#pragma unroll
            for (int n = 0; n < TN; n++) acc[m][n] += a[m] * b[n];
    }
#pragma unroll
    for (int m = 0; m < TM; m++) {
        int node = base + r0 + m;
        if (node >= N) continue;
#pragma unroll
        for (int n = 0; n < TN; n++) {
            float v = acc[m][n];
            if (BIAS) v += ldf(bias, isbf, c0 + n);
            if (ELU) v = (v > 0.0f) ? v : expm1f(v);
            H[(size_t)node * FOUT + c0 + n] = v;
        }
    }
}

// diagnostic fallback: if ws_size too small, emit sentinel 123.0
__global__ void k_sentinel(float* out, int n) {
    int i = blockIdx.x * blockDim.x + threadIdx.x;
    if (i < n) out[i] = 123.0f;
}

extern "C" void kernel_launch(void* const* d_in, const int* in_sizes, int n_in,
                              void* d_out, int out_size, void* d_ws, size_t ws_size,
                              hipStream_t stream) {
    const void* x  = d_in[0];
    const void* ei = d_in[1];
    const void* ea = d_in[2];
    const void* W1 = d_in[3];
    const void* b1 = d_in[4];
    const void* W2 = d_in[5];
    const void* b2 = d_in[6];
    const void* W3 = d_in[7];
    const void* b3 = d_in[8];
    float* out = (float*)d_out;

    // workspace layout (256B aligned)
    char* ws = (char*)d_ws;
    size_t off = 0;
    auto alloc = [&](size_t bytes) {
        off = (off + 255) & ~(size_t)255;
        size_t r = off;
        off += bytes;
        return r;
    };
    float* dinv    = (float*)(ws + alloc((size_t)N * 4));
    int*   bkt_cnt = (int*)  (ws + alloc((size_t)NBKT * 4));
    int*   bkt_off = (int*)  (ws + alloc((size_t)(NBKT + 1) * 4));
    int*   bkt_cur = (int*)  (ws + alloc((size_t)NBKT * 4));
    int*   flags   = (int*)  (ws + alloc(256));
    int2*  tmp     = (int2*) (ws + alloc((size_t)E * 8));      // lives all 3 aggs
    float* bufA    = (float*)(ws + alloc((size_t)N * 64 * 4));
    float* bufB    = (float*)(ws + alloc((size_t)N * 64 * 4));
    size_t need = off;

    if (ws_size < need) {
        hipLaunchKernelGGL(k_sentinel, dim3((N * 128 + 255) / 256), dim3(256), 0, stream,
                           out, N * 128);
        return;
    }

    const int gH = (E + HIST_EPB - 1) / HIST_EPB;   // 391
    const int gS = (E + SC_EPB - 1) / SC_EPB;       // 196

    hipLaunchKernelGGL(k_probe, dim3(1), dim3(256), 0, stream, ei, x, flags, bkt_cnt);
    hipLaunchKernelGGL(k_hist, dim3(gH), dim3(256), 0, stream, ei, flags, bkt_cnt);
    hipLaunchKernelGGL(k_bscan, dim3(1), dim3(256), 0, stream, bkt_cnt, bkt_off, bkt_cur);
    hipLaunchKernelGGL(k_scatter, dim3(gS), dim3(256), 0, stream, ei, flags, ea, bkt_cur, tmp);
    hipLaunchKernelGGL(k_dinv2, dim3(NBKT), dim3(256), 0, stream, tmp, bkt_off, dinv);

    // L1: t1 = x@W1 (bufA, F=32); a1 = ELU(agg(t1)+b1) (bufB)
    hipLaunchKernelGGL((k_gemm<128, 32, 2, 4, true, false, false>),
                       dim3((N + 63) / 64), dim3(256), 0, stream, x, W1, nullptr, flags, bufA);
    hipLaunchKernelGGL((k_aggb<32, true, true>), dim3(NBKT), dim3(512), 0, stream,
                       (const float4*)bufA, tmp, bkt_off, dinv, b1, flags, (float4*)bufB);
    // L2: s2 = agg(a1) (bufA, F=32); h2 = ELU(s2@W2+b2) (bufB, F=64)
    hipLaunchKernelGGL((k_aggb<32, false, false>), dim3(NBKT), dim3(512), 0, stream,
                       (const float4*)bufB, tmp, bkt_off, dinv, nullptr, flags, (float4*)bufA);
    hipLaunchKernelGGL((k_gemm<32, 64, 4, 4, false, true, true>),
                       dim3((N + 63) / 64), dim3(256), 0, stream, bufA, W2, b2, flags, bufB);
    // L3: s3 = agg(h2) (bufA, F=64); out = s3@W3+b3 (d_out, F=128)
    hipLaunchKernelGGL((k_aggb<64, false, false>), dim3(NBKT), dim3(512), 0, stream,
                       (const float4*)bufB, tmp, bkt_off, dinv, nullptr, flags, (float4*)bufA);
    hipLaunchKernelGGL((k_gemm<64, 128, 4, 8, false, true, false>),
                       dim3((N + 63) / 64), dim3(256), 0, stream, bufA, W3, b3, flags, out);
}

// Round 3
// 601.985 us; speedup vs baseline: 5.0127x; 5.0127x over previous
//
#include <hip/hip_runtime.h>
#include <hip/hip_bf16.h>

// GCN 3-layer: gcn_norm -> (GCNConv, ELU) x2 -> GCNConv
// N=100000, E=3200000, dims 128->32->64->128.
// agg is linear => aggregate in the SMALLER feature dim per layer:
//   L1: t1 = x@W1 (128->32); a1 = ELU(agg(t1) + b1)          [gather F=32]
//   L2: s2 = agg(a1);        h2 = ELU(s2@W2 + b2)            [gather F=32]
//   L3: s3 = agg(h2);        out = s3@W3 + b3                [gather F=64]
//
// CSR build: bucketed 2-level counting sort (k_hist -> k_bscan ->
// k_scatter -> k_nodecnt -> k_fill2), all LDS-histogram based; epk holds
// (src, dinv[src]*ew) per edge in CSR order. 200MB -> 26MB write traffic
// vs the single-pass sort (round-0 fix).
//
// Round-2 LESSON (reverted): edge-parallel agg with LDS f32 atomicAdd was
// 12x SLOWER (ds_add_f32 ~0.25 ops/cy/CU measured) — LDS float atomics
// are the bottleneck, never use for E*F-scale accumulation.
//
// Round-3: node-parallel agg (round-1 structure) but LATENCY-optimized:
// the 4-deep unroll stalled on a vmcnt drain every 4 gathers (45% BW,
// VALU 12%, F=32 aggs ~same time as F=64 => latency-bound not BW-bound).
// Now: unroll 8 + explicit software pipeline (next 8 epk entries load
// BEFORE current gathers are accumulated) + dual accumulators.
// GEMMs register-blocked 64-row tiles. Inputs: fp32 (probed vs bf16),
// edge_index i64 (probed vs i32). Output fp32.

constexpr int N = 100000;
constexpr int E = 3200000;

constexpr int BSHIFT = 7;
constexpr int BSIZE = 128;                       // nodes per bucket
constexpr int NBKT = (N + BSIZE - 1) / BSIZE;    // 782

constexpr float FIX_SCALE = 16777216.0f;         // 2^24

constexpr int HIST_EPB = 8192;                   // edges per block, hist
constexpr int SC_EPB = 16384;                    // edges per block, scatter

__device__ __forceinline__ float ldf(const void* p, int isbf, size_t i) {
    return isbf ? __bfloat162float(((const __hip_bfloat16*)p)[i])
                : ((const float*)p)[i];
}

__device__ __forceinline__ int ld_idx(const void* ei, int is64, size_t pos) {
    return is64 ? (int)((const long long*)ei)[pos] : ((const int*)ei)[pos];
}

// flags[0] = is64 (edge_index), flags[1] = isbf (float tensors)
// also zeroes the bucket-count array (runs before k_hist on the stream)
__global__ void k_probe(const void* ei, const void* x, int* flags, int* bkt_cnt) {
    __shared__ int bad64, bigcnt;
    int t = threadIdx.x;
    if (t == 0) { bad64 = 0; bigcnt = 0; }
    __syncthreads();
    long long v = ((const long long*)ei)[t];
    if (v < 0 || v >= (long long)N) atomicAdd(&bad64, 1);
    const unsigned short* u = (const unsigned short*)x;
    int big = 0;
    for (int i = t * 16; i < t * 16 + 16; i++) {
        int e = (u[i] >> 7) & 0xFF;
        if (e >= 133) big++;
    }
    atomicAdd(&bigcnt, big);
    for (int i = t; i < NBKT; i += 256) bkt_cnt[i] = 0;
    __syncthreads();
    if (t == 0) { flags[0] = (bad64 == 0) ? 1 : 0; flags[1] = (bigcnt < 40) ? 1 : 0; }
}

// bucket histogram: LDS per block, one global atomic per (block,bucket)
__global__ __launch_bounds__(256) void k_hist(const void* ei, const int* flags,
                                              int* bkt_cnt) {
    __shared__ int h[NBKT];
    int t = threadIdx.x;
    for (int i = t; i < NBKT; i += 256) h[i] = 0;
    __syncthreads();
    int is64 = flags[0];
    size_t eb = (size_t)blockIdx.x * HIST_EPB;
#pragma unroll 4
    for (int k = 0; k < HIST_EPB / 256; k++) {
        size_t e = eb + t + (size_t)k * 256;
        if (e < (size_t)E) {
            int c = ld_idx(ei, is64, (size_t)E + e);
            atomicAdd(&h[c >> BSHIFT], 1);
        }
    }
    __syncthreads();
    for (int i = t; i < NBKT; i += 256) {
        int v = h[i];
        if (v) atomicAdd(&bkt_cnt[i], v);
    }
}

// single-block exclusive scan over NBKT buckets -> bkt_off, bkt_cur
__global__ void k_bscan(const int* bkt_cnt, int* bkt_off, int* bkt_cur) {
    __shared__ int s[256];
    int t = threadIdx.x;
    int v[4]; int sum = 0;
#pragma unroll
    for (int j = 0; j < 4; j++) {
        int i = t * 4 + j;
        v[j] = (i < NBKT) ? bkt_cnt[i] : 0;
        sum += v[j];
    }
    s[t] = sum; __syncthreads();
    for (int st = 1; st < 256; st <<= 1) {
        int add = (t >= st) ? s[t - st] : 0;
        __syncthreads();
        s[t] += add;
        __syncthreads();
    }
    int excl = s[t] - sum;
#pragma unroll
    for (int j = 0; j < 4; j++) {
        int i = t * 4 + j;
        if (i < NBKT) { bkt_off[i] = excl; bkt_cur[i] = excl; excl += v[j]; }
    }
    if (t == 0) bkt_off[NBKT] = E;
}

// bucket-sort edges into tmp[]: per-block LDS histogram, one run
// reservation atomic per (block,bucket), dense run writes.
// tmp entry: .x = r | (c&127)<<17  (r<2^17, fits), .y = w bits
__global__ __launch_bounds__(256) void k_scatter(const void* ei, const int* flags,
                                                 const void* ew, int* bkt_cur,
                                                 int2* tmp) {
    __shared__ int h[NBKT];
    __shared__ int base_s[NBKT];
    int t = threadIdx.x;
    for (int i = t; i < NBKT; i += 256) h[i] = 0;
    __syncthreads();
    int is64 = flags[0], isbf = flags[1];
    size_t eb = (size_t)blockIdx.x * SC_EPB;
    int nb = (int)min((size_t)SC_EPB, (size_t)E - eb);
    // pass 1: local histogram
    for (int k = t; k < nb; k += 256) {
        int c = ld_idx(ei, is64, (size_t)E + eb + k);
        atomicAdd(&h[c >> BSHIFT], 1);
    }
    __syncthreads();
    // reserve a dense run per bucket
    for (int i = t; i < NBKT; i += 256) {
        int v = h[i];
        base_s[i] = v ? atomicAdd(&bkt_cur[i], v) : 0;
    }
    __syncthreads();
    for (int i = t; i < NBKT; i += 256) h[i] = 0;
    __syncthreads();
    // pass 2: place edges within reserved runs
    for (int k = t; k < nb; k += 256) {
        size_t e = eb + k;
        int r = ld_idx(ei, is64, e);
        int c = ld_idx(ei, is64, (size_t)E + e);
        float w = ldf(ew, isbf, e);
        int b = c >> BSHIFT;
        int loc = atomicAdd(&h[b], 1);
        int pos = base_s[b] + loc;
        tmp[pos] = make_int2(r | ((c & (BSIZE - 1)) << 17), __float_as_int(w));
    }
}

// per bucket: node counts + fixed-point weight sums (LDS atomics only —
// int atomics here, cheap at this scale), 128-wide LDS scan -> offsets;
// dinv = rsqrt(1 + wsum) (bit-identical to the original packed scheme)
__global__ __launch_bounds__(256) void k_nodecnt(const int2* __restrict__ tmp,
                                                 const int* __restrict__ bkt_off,
                                                 int* __restrict__ counts,
                                                 int* __restrict__ offsets,
                                                 float* __restrict__ dinv) {
    __shared__ int cnt_s[BSIZE];
    __shared__ unsigned int wfx_s[BSIZE];
    __shared__ int sc_s[BSIZE];
    int t = threadIdx.x;
    int b = blockIdx.x;
    if (t < BSIZE) { cnt_s[t] = 0; wfx_s[t] = 0u; }
    __syncthreads();
    int s0 = bkt_off[b], s1 = bkt_off[b + 1];
    for (int p = s0 + t; p < s1; p += 256) {
        int2 ev = tmp[p];
        int c7 = (int)(((unsigned)ev.x) >> 17);
        float w = __int_as_float(ev.y);
        atomicAdd(&cnt_s[c7], 1);
        atomicAdd(&wfx_s[c7], (unsigned)__float2uint_rn(w * FIX_SCALE));
    }
    __syncthreads();
    if (t < BSIZE) sc_s[t] = cnt_s[t];
    __syncthreads();
    for (int st = 1; st < BSIZE; st <<= 1) {
        int add = (t < BSIZE && t >= st) ? sc_s[t - st] : 0;
        __syncthreads();
        if (t < BSIZE) sc_s[t] += add;
        __syncthreads();
    }
    if (t < BSIZE) {
        int node = b * BSIZE + t;
        if (node < N) {
            int c = cnt_s[t];
            offsets[node] = s0 + sc_s[t] - c;   // bucket base + exclusive
            counts[node] = c;
            float deg = 1.0f + (float)wfx_s[t] * (1.0f / FIX_SCALE);
            dinv[node] = rsqrtf(deg);
        }
    }
}

// per bucket: fill CSR epk[pos] = (src, dinv[src]*ew). Destination range
// is the bucket's contiguous ~32KB slice of epk -> block-private, dense.
__global__ __launch_bounds__(256) void k_fill2(const int2* __restrict__ tmp,
                                               const int* __restrict__ bkt_off,
                                               const int* __restrict__ offsets,
                                               const float* __restrict__ dinv,
                                               int2* __restrict__ epk) {
    __shared__ int lcur[BSIZE];
    int t = threadIdx.x;
    int b = blockIdx.x;
    if (t < BSIZE) {
        int node = b * BSIZE + t;
        lcur[t] = (node < N) ? offsets[node] : 0;
    }
    __syncthreads();
    int s0 = bkt_off[b], s1 = bkt_off[b + 1];
    for (int p = s0 + t; p < s1; p += 256) {
        int2 ev = tmp[p];
        unsigned px = (unsigned)ev.x;
        int r = (int)(px & 0x1FFFFu);
        int c7 = (int)(px >> 17);
        float w = __int_as_float(ev.y);
        float nr = dinv[r] * w;
        int pos = atomicAdd(&lcur[c7], 1);
        epk[pos] = make_int2(r, __float_as_int(nr));
    }
}

// --- register-blocked GEMM: H[N,FOUT] = X[N,FIN] @ W[FIN,FOUT] (+b, ELU)
template <int FIN, int FOUT, int TM, int TN, bool ADAPT, bool BIAS, bool ELU>
__global__ __launch_bounds__(256) void k_gemm(const void* __restrict__ X,
                                              const void* __restrict__ W,
                                              const void* __restrict__ bias,
                                              const int* __restrict__ flags,
                                              float* __restrict__ H) {
    constexpr int TCOLS = FOUT / TN;
    constexpr int TROWS = 256 / TCOLS;
    constexpr int BR = TROWS * TM;
    __shared__ float wl[FIN * FOUT];
    __shared__ float xt[FIN][BR + 1];
    int t = threadIdx.x;
    int isbf = flags[1];
    int base = blockIdx.x * BR;

    if (!isbf) {
        const float4* W4 = (const float4*)W;
        float4* wl4 = (float4*)wl;
        for (int i = t; i < FIN * FOUT / 4; i += 256) wl4[i] = W4[i];
    } else {
        for (int i = t; i < FIN * FOUT; i += 256)
            wl[i] = __bfloat162float(((const __hip_bfloat16*)W)[i]);
    }
    if (!ADAPT || !isbf) {
        const float4* X4 = (const float4*)X;
        for (int i = t; i < BR * FIN / 4; i += 256) {
            int row = i / (FIN / 4);
            int kq = i % (FIN / 4);
            int node = base + row;
            float4 v = make_float4(0.f, 0.f, 0.f, 0.f);
            if (node < N) v = X4[(size_t)node * (FIN / 4) + kq];
            int k = kq * 4;
            xt[k][row] = v.x; xt[k + 1][row] = v.y;
            xt[k + 2][row] = v.z; xt[k + 3][row] = v.w;
        }
    } else {
        for (int i = t; i < BR * FIN; i += 256) {
            int row = i / FIN, k = i % FIN;
            int node = base + row;
            float v = (node < N)
                ? __bfloat162float(((const __hip_bfloat16*)X)[(size_t)node * FIN + k]) : 0.f;
            xt[k][row] = v;
        }
    }
    __syncthreads();

    int tcol = t % TCOLS, trow = t / TCOLS;
    int r0 = trow * TM, c0 = tcol * TN;
    float acc[TM][TN] = {};
#pragma unroll 4
    for (int k = 0; k < FIN; k++) {
        float a[TM], b[TN];
#pragma unroll
        for (int m = 0; m < TM; m++) a[m] = xt[k][r0 + m];
#pragma unroll
        for (int n = 0; n < TN; n++) b[n] = wl[k * FOUT + c0 + n];
#pragma unroll
        for (int m = 0; m < TM; m++)
#pragma unroll
            for (int n = 0; n < TN; n++) acc[m][n] += a[m] * b[n];
    }
#pragma unroll
    for (int m = 0; m < TM; m++) {
        int node = base + r0 + m;
        if (node >= N) continue;
#pragma unroll
        for (int n = 0; n < TN; n++) {
            float v = acc[m][n];
            if (BIAS) v += ldf(bias, isbf, c0 + n);
            if (ELU) v = (v > 0.0f) ? v : expm1f(v);
            H[(size_t)node * FOUT + c0 + n] = v;
        }
    }
}

// --- aggregation: out[n] = di*Σ_e w'_e*H[src_e] + di^2*H[n] (+b, ELU)
// (w' = dinv[src]*ew stored in CSR; dinv[target]=di applied here once)
// Node-parallel, LPN lanes per node. Latency-optimized: unroll 8 with an
// explicit software pipeline — the NEXT batch's 8 epk entries are loaded
// before the current batch's gathers are accumulated, so the address
// stream never stalls behind the vmcnt drain. Dual accumulators.
template <int F, bool BIAS, bool ELU>
__global__ __launch_bounds__(256) void k_agg(const float4* __restrict__ H4,
                                             const int* __restrict__ offsets,
                                             const int* __restrict__ counts,
                                             const int2* __restrict__ epk,
                                             const float* __restrict__ dinv,
                                             const void* __restrict__ bias,
                                             const int* __restrict__ flags,
                                             float4* __restrict__ out4) {
    constexpr int LPN = F / 4;        // lanes per node
    constexpr int NPB = 256 / LPN;    // nodes per block
    constexpr int STR = F / 4;        // float4 stride per row
    int t = threadIdx.x;
    int lane = t % LPN;
    int g = t / LPN;
    int node = blockIdx.x * NPB + g;
    if (node >= N) return;
    float di = dinv[node];
    float4 h = H4[(size_t)node * STR + lane];
    float4 acc0 = make_float4(0.f, 0.f, 0.f, 0.f);
    float4 acc1 = make_float4(0.f, 0.f, 0.f, 0.f);
    int p = offsets[node];
    int pend = p + counts[node];

    int2 eA[8];
    bool have = (p + 8 <= pend);
    if (have) {
#pragma unroll
        for (int j = 0; j < 8; j++) eA[j] = epk[p + j];
    }
    while (have) {
        // issue 8 independent gathers
        float4 gg[8];
#pragma unroll
        for (int j = 0; j < 8; j++)
            gg[j] = H4[(size_t)eA[j].x * STR + lane];
        float w[8];
#pragma unroll
        for (int j = 0; j < 8; j++) w[j] = __int_as_float(eA[j].y);
        p += 8;
        bool nxt = (p + 8 <= pend);
        int2 eB[8];
        if (nxt) {
#pragma unroll
            for (int j = 0; j < 8; j++) eB[j] = epk[p + j];
        }
        // accumulate current batch (drains gather vmcnt; next epk loads
        // are already in flight above)
#pragma unroll
        for (int j = 0; j < 8; j += 2) {
            acc0.x += gg[j].x * w[j]; acc0.y += gg[j].y * w[j];
            acc0.z += gg[j].z * w[j]; acc0.w += gg[j].w * w[j];
            acc1.x += gg[j + 1].x * w[j + 1]; acc1.y += gg[j + 1].y * w[j + 1];
            acc1.z += gg[j + 1].z * w[j + 1]; acc1.w += gg[j + 1].w * w[j + 1];
        }
#pragma unroll
        for (int j = 0; j < 8; j++) eA[j] = eB[j];
        have = nxt;
    }
    // tail: 4-wide then scalar
    for (; p + 4 <= pend; p += 4) {
        int2 e0 = epk[p], e1 = epk[p + 1], e2 = epk[p + 2], e3 = epk[p + 3];
        float4 h0 = H4[(size_t)e0.x * STR + lane];
        float4 h1 = H4[(size_t)e1.x * STR + lane];
        float4 h2 = H4[(size_t)e2.x * STR + lane];
        float4 h3 = H4[(size_t)e3.x * STR + lane];
        float w0 = __int_as_float(e0.y), w1 = __int_as_float(e1.y);
        float w2 = __int_as_float(e2.y), w3 = __int_as_float(e3.y);
        acc0.x += h0.x * w0 + h2.x * w2; acc1.x += h1.x * w1 + h3.x * w3;
        acc0.y += h0.y * w0 + h2.y * w2; acc1.y += h1.y * w1 + h3.y * w3;
        acc0.z += h0.z * w0 + h2.z * w2; acc1.z += h1.z * w1 + h3.z * w3;
        acc0.w += h0.w * w0 + h2.w * w2; acc1.w += h1.w * w1 + h3.w * w3;
    }
    for (; p < pend; p++) {
        int2 e = epk[p];
        float4 hh = H4[(size_t)e.x * STR + lane];
        float w = __int_as_float(e.y);
        acc0.x += hh.x * w; acc0.y += hh.y * w;
        acc0.z += hh.z * w; acc0.w += hh.w * w;
    }
    float4 acc;
    acc.x = acc0.x + acc1.x; acc.y = acc0.y + acc1.y;
    acc.z = acc0.z + acc1.z; acc.w = acc0.w + acc1.w;
    float sw = di * di;
    acc.x = acc.x * di + h.x * sw;
    acc.y = acc.y * di + h.y * sw;
    acc.z = acc.z * di + h.z * sw;
    acc.w = acc.w * di + h.w * sw;
    if (BIAS) {
        int fb = lane * 4;
        int isbf = flags[1];
        acc.x += ldf(bias, isbf, fb);
        acc.y += ldf(bias, isbf, fb + 1);
        acc.z += ldf(bias, isbf, fb + 2);
        acc.w += ldf(bias, isbf, fb + 3);
    }
    if (ELU) {
        acc.x = (acc.x > 0.0f) ? acc.x : expm1f(acc.x);
        acc.y = (acc.y > 0.0f) ? acc.y : expm1f(acc.y);
        acc.z = (acc.z > 0.0f) ? acc.z : expm1f(acc.z);
        acc.w = (acc.w > 0.0f) ? acc.w : expm1f(acc.w);
    }
    out4[(size_t)node * STR + lane] = acc;
}

// diagnostic fallback: if ws_size too small, emit sentinel 123.0
__global__ void k_sentinel(float* out, int n) {
    int i = blockIdx.x * blockDim.x + threadIdx.x;
    if (i < n) out[i] = 123.0f;
}

extern "C" void kernel_launch(void* const* d_in, const int* in_sizes, int n_in,
                              void* d_out, int out_size, void* d_ws, size_t ws_size,
                              hipStream_t stream) {
    const void* x  = d_in[0];
    const void* ei = d_in[1];
    const void* ea = d_in[2];
    const void* W1 = d_in[3];
    const void* b1 = d_in[4];
    const void* W2 = d_in[5];
    const void* b2 = d_in[6];
    const void* W3 = d_in[7];
    const void* b3 = d_in[8];
    float* out = (float*)d_out;

    // workspace layout (256B aligned)
    char* ws = (char*)d_ws;
    size_t off = 0;
    auto alloc = [&](size_t bytes) {
        off = (off + 255) & ~(size_t)255;
        size_t r = off;
        off += bytes;
        return r;
    };
    float* dinv    = (float*)(ws + alloc((size_t)N * 4));
    int*   counts  = (int*)  (ws + alloc((size_t)N * 4));
    int*   offsets = (int*)  (ws + alloc((size_t)N * 4));
    int*   bkt_cnt = (int*)  (ws + alloc((size_t)NBKT * 4));
    int*   bkt_off = (int*)  (ws + alloc((size_t)(NBKT + 1) * 4));
    int*   bkt_cur = (int*)  (ws + alloc((size_t)NBKT * 4));
    int*   flags   = (int*)  (ws + alloc(256));
    int2*  epk     = (int2*) (ws + alloc((size_t)E * 8));
    float* bufA    = (float*)(ws + alloc((size_t)N * 64 * 4));
    float* bufB    = (float*)(ws + alloc((size_t)N * 64 * 4));
    size_t need = off;
    // tmp (bucket-sorted edges, E*8B = 25.6MB) aliases bufA (N*64*4 = 25.6MB):
    // tmp's last read (k_fill2) precedes bufA's first write (L1 GEMM).
    int2* tmp = (int2*)bufA;

    if (ws_size < need) {
        hipLaunchKernelGGL(k_sentinel, dim3((N * 128 + 255) / 256), dim3(256), 0, stream,
                           out, N * 128);
        return;
    }

    const int gH = (E + HIST_EPB - 1) / HIST_EPB;   // 391
    const int gS = (E + SC_EPB - 1) / SC_EPB;       // 196

    hipLaunchKernelGGL(k_probe, dim3(1), dim3(256), 0, stream, ei, x, flags, bkt_cnt);
    hipLaunchKernelGGL(k_hist, dim3(gH), dim3(256), 0, stream, ei, flags, bkt_cnt);
    hipLaunchKernelGGL(k_bscan, dim3(1), dim3(256), 0, stream, bkt_cnt, bkt_off, bkt_cur);
    hipLaunchKernelGGL(k_scatter, dim3(gS), dim3(256), 0, stream, ei, flags, ea, bkt_cur, tmp);
    hipLaunchKernelGGL(k_nodecnt, dim3(NBKT), dim3(256), 0, stream, tmp, bkt_off,
                       counts, offsets, dinv);
    hipLaunchKernelGGL(k_fill2, dim3(NBKT), dim3(256), 0, stream, tmp, bkt_off,
                       offsets, dinv, epk);

    // L1: t1 = x@W1 (bufA, F=32); a1 = ELU(agg(t1)+b1) (bufB)
    hipLaunchKernelGGL((k_gemm<128, 32, 2, 4, true, false, false>),
                       dim3((N + 63) / 64), dim3(256), 0, stream, x, W1, nullptr, flags, bufA);
    hipLaunchKernelGGL((k_agg<32, true, true>), dim3((N + 31) / 32), dim3(256), 0, stream,
                       (const float4*)bufA, offsets, counts, epk, dinv, b1, flags, (float4*)bufB);
    // L2: s2 = agg(a1) (bufA, F=32); h2 = ELU(s2@W2+b2) (bufB, F=64)
    hipLaunchKernelGGL((k_agg<32, false, false>), dim3((N + 31) / 32), dim3(256), 0, stream,
                       (const float4*)bufB, offsets, counts, epk, dinv, nullptr, flags, (float4*)bufA);
    hipLaunchKernelGGL((k_gemm<32, 64, 4, 4, false, true, true>),
                       dim3((N + 63) / 64), dim3(256), 0, stream, bufA, W2, b2, flags, bufB);
    // L3: s3 = agg(h2) (bufA, F=64); out = s3@W3+b3 (d_out, F=128)
    hipLaunchKernelGGL((k_agg<64, false, false>), dim3((N + 15) / 16), dim3(256), 0, stream,
                       (const float4*)bufB, offsets, counts, epk, dinv, nullptr, flags, (float4*)bufA);
    hipLaunchKernelGGL((k_gemm<64, 128, 4, 8, false, true, false>),
                       dim3((N + 63) / 64), dim3(256), 0, stream, bufA, W3, b3, flags, out);
}

// Round 4
// 508.898 us; speedup vs baseline: 5.9296x; 1.1829x over previous
//
#include <hip/hip_runtime.h>
#include <hip/hip_bf16.h>

// GCN 3-layer: gcn_norm -> (GCNConv, ELU) x2 -> GCNConv
// N=100000, E=3200000, dims 128->32->64->128.
// agg is linear => aggregate in the SMALLER feature dim per layer:
//   L1: t1 = x@W1 (128->32); a1 = ELU(agg(t1) + b1)          [gather F=32]
//   L2: s2 = agg(a1);        h2 = ELU(s2@W2 + b2)            [gather F=32]
//   L3: s3 = agg(h2);        out = s3@W3 + b3                [gather F=64]
//
// CSR build: bucketed 2-level counting sort (k_hist -> k_bscan ->
// k_scatter -> k_nodecnt -> k_fill2); epk holds (src, dinv[src]*ew).
//
// LESSONS:
//  - r2: LDS f32 atomicAdd agg = 12x slower (ds_add_f32 ~0.25 ops/cy/CU).
//  - r3: deep SW pipelining of gathers gained only 7% (116->108us, BW
//    stuck ~47%): agg is near the compulsory-traffic ceiling for the
//    random-gather pattern (372MB fetched vs ~230MB floor = 8 XCDs x H
//    + epk). Latency engineering is exhausted; cut BYTES instead.
//  - r4 (this): intermediate feature buffers in BF16 (storage only).
//    All accumulation fp32 (GEMM acc, agg acc, epk weights, dinv).
//    Gather/selfloop/agg-write and internal GEMM I/O traffic halves.
// GEMMs register-blocked 64-row tiles. Inputs: fp32 (probed vs bf16),
// edge_index i64 (probed vs i32). Output fp32.

constexpr int N = 100000;
constexpr int E = 3200000;

constexpr int BSHIFT = 7;
constexpr int BSIZE = 128;                       // nodes per bucket
constexpr int NBKT = (N + BSIZE - 1) / BSIZE;    // 782

constexpr float FIX_SCALE = 16777216.0f;         // 2^24

constexpr int HIST_EPB = 8192;                   // edges per block, hist
constexpr int SC_EPB = 16384;                    // edges per block, scatter

__device__ __forceinline__ float ldf(const void* p, int isbf, size_t i) {
    return isbf ? __bfloat162float(((const __hip_bfloat16*)p)[i])
                : ((const float*)p)[i];
}

__device__ __forceinline__ int ld_idx(const void* ei, int is64, size_t pos) {
    return is64 ? (int)((const long long*)ei)[pos] : ((const int*)ei)[pos];
}

// --- bf16x4 pack/unpack (manual RNE, no API dependence) ---
__device__ __forceinline__ float4 bf4tof4(uint2 u) {
    float4 r;
    r.x = __uint_as_float(u.x << 16);
    r.y = __uint_as_float(u.x & 0xffff0000u);
    r.z = __uint_as_float(u.y << 16);
    r.w = __uint_as_float(u.y & 0xffff0000u);
    return r;
}
__device__ __forceinline__ unsigned short f2bf(float f) {
    unsigned u = __float_as_uint(f);
    unsigned rnd = 0x7fffu + ((u >> 16) & 1u);
    return (unsigned short)((u + rnd) >> 16);
}
__device__ __forceinline__ unsigned packbf2(float a, float b) {
    return (unsigned)f2bf(a) | ((unsigned)f2bf(b) << 16);
}
__device__ __forceinline__ uint2 f4tobf4(float4 v) {
    uint2 r;
    r.x = packbf2(v.x, v.y);
    r.y = packbf2(v.z, v.w);
    return r;
}

// flags[0] = is64 (edge_index), flags[1] = isbf (float tensors)
// also zeroes the bucket-count array (runs before k_hist on the stream)
__global__ void k_probe(const void* ei, const void* x, int* flags, int* bkt_cnt) {
    __shared__ int bad64, bigcnt;
    int t = threadIdx.x;
    if (t == 0) { bad64 = 0; bigcnt = 0; }
    __syncthreads();
    long long v = ((const long long*)ei)[t];
    if (v < 0 || v >= (long long)N) atomicAdd(&bad64, 1);
    const unsigned short* u = (const unsigned short*)x;
    int big = 0;
    for (int i = t * 16; i < t * 16 + 16; i++) {
        int e = (u[i] >> 7) & 0xFF;
        if (e >= 133) big++;
    }
    atomicAdd(&bigcnt, big);
    for (int i = t; i < NBKT; i += 256) bkt_cnt[i] = 0;
    __syncthreads();
    if (t == 0) { flags[0] = (bad64 == 0) ? 1 : 0; flags[1] = (bigcnt < 40) ? 1 : 0; }
}

// bucket histogram: LDS per block, one global atomic per (block,bucket)
__global__ __launch_bounds__(256) void k_hist(const void* ei, const int* flags,
                                              int* bkt_cnt) {
    __shared__ int h[NBKT];
    int t = threadIdx.x;
    for (int i = t; i < NBKT; i += 256) h[i] = 0;
    __syncthreads();
    int is64 = flags[0];
    size_t eb = (size_t)blockIdx.x * HIST_EPB;
#pragma unroll 4
    for (int k = 0; k < HIST_EPB / 256; k++) {
        size_t e = eb + t + (size_t)k * 256;
        if (e < (size_t)E) {
            int c = ld_idx(ei, is64, (size_t)E + e);
            atomicAdd(&h[c >> BSHIFT], 1);
        }
    }
    __syncthreads();
    for (int i = t; i < NBKT; i += 256) {
        int v = h[i];
        if (v) atomicAdd(&bkt_cnt[i], v);
    }
}

// single-block exclusive scan over NBKT buckets -> bkt_off, bkt_cur
__global__ void k_bscan(const int* bkt_cnt, int* bkt_off, int* bkt_cur) {
    __shared__ int s[256];
    int t = threadIdx.x;
    int v[4]; int sum = 0;
#pragma unroll
    for (int j = 0; j < 4; j++) {
        int i = t * 4 + j;
        v[j] = (i < NBKT) ? bkt_cnt[i] : 0;
        sum += v[j];
    }
    s[t] = sum; __syncthreads();
    for (int st = 1; st < 256; st <<= 1) {
        int add = (t >= st) ? s[t - st] : 0;
        __syncthreads();
        s[t] += add;
        __syncthreads();
    }
    int excl = s[t] - sum;
#pragma unroll
    for (int j = 0; j < 4; j++) {
        int i = t * 4 + j;
        if (i < NBKT) { bkt_off[i] = excl; bkt_cur[i] = excl; excl += v[j]; }
    }
    if (t == 0) bkt_off[NBKT] = E;
}

// bucket-sort edges into tmp[]: per-block LDS histogram, one run
// reservation atomic per (block,bucket), dense run writes.
// tmp entry: .x = r | (c&127)<<17  (r<2^17, fits), .y = w bits
__global__ __launch_bounds__(256) void k_scatter(const void* ei, const int* flags,
                                                 const void* ew, int* bkt_cur,
                                                 int2* tmp) {
    __shared__ int h[NBKT];
    __shared__ int base_s[NBKT];
    int t = threadIdx.x;
    for (int i = t; i < NBKT; i += 256) h[i] = 0;
    __syncthreads();
    int is64 = flags[0], isbf = flags[1];
    size_t eb = (size_t)blockIdx.x * SC_EPB;
    int nb = (int)min((size_t)SC_EPB, (size_t)E - eb);
    // pass 1: local histogram
    for (int k = t; k < nb; k += 256) {
        int c = ld_idx(ei, is64, (size_t)E + eb + k);
        atomicAdd(&h[c >> BSHIFT], 1);
    }
    __syncthreads();
    // reserve a dense run per bucket
    for (int i = t; i < NBKT; i += 256) {
        int v = h[i];
        base_s[i] = v ? atomicAdd(&bkt_cur[i], v) : 0;
    }
    __syncthreads();
    for (int i = t; i < NBKT; i += 256) h[i] = 0;
    __syncthreads();
    // pass 2: place edges within reserved runs
    for (int k = t; k < nb; k += 256) {
        size_t e = eb + k;
        int r = ld_idx(ei, is64, e);
        int c = ld_idx(ei, is64, (size_t)E + e);
        float w = ldf(ew, isbf, e);
        int b = c >> BSHIFT;
        int loc = atomicAdd(&h[b], 1);
        int pos = base_s[b] + loc;
        tmp[pos] = make_int2(r | ((c & (BSIZE - 1)) << 17), __float_as_int(w));
    }
}

// per bucket: node counts + fixed-point weight sums (LDS int atomics,
// cheap at this scale), 128-wide LDS scan -> offsets;
// dinv = rsqrt(1 + wsum) (bit-identical to the original packed scheme)
__global__ __launch_bounds__(256) void k_nodecnt(const int2* __restrict__ tmp,
                                                 const int* __restrict__ bkt_off,
                                                 int* __restrict__ counts,
                                                 int* __restrict__ offsets,
                                                 float* __restrict__ dinv) {
    __shared__ int cnt_s[BSIZE];
    __shared__ unsigned int wfx_s[BSIZE];
    __shared__ int sc_s[BSIZE];
    int t = threadIdx.x;
    int b = blockIdx.x;
    if (t < BSIZE) { cnt_s[t] = 0; wfx_s[t] = 0u; }
    __syncthreads();
    int s0 = bkt_off[b], s1 = bkt_off[b + 1];
    for (int p = s0 + t; p < s1; p += 256) {
        int2 ev = tmp[p];
        int c7 = (int)(((unsigned)ev.x) >> 17);
        float w = __int_as_float(ev.y);
        atomicAdd(&cnt_s[c7], 1);
        atomicAdd(&wfx_s[c7], (unsigned)__float2uint_rn(w * FIX_SCALE));
    }
    __syncthreads();
    if (t < BSIZE) sc_s[t] = cnt_s[t];
    __syncthreads();
    for (int st = 1; st < BSIZE; st <<= 1) {
        int add = (t < BSIZE && t >= st) ? sc_s[t - st] : 0;
        __syncthreads();
        if (t < BSIZE) sc_s[t] += add;
        __syncthreads();
    }
    if (t < BSIZE) {
        int node = b * BSIZE + t;
        if (node < N) {
            int c = cnt_s[t];
            offsets[node] = s0 + sc_s[t] - c;   // bucket base + exclusive
            counts[node] = c;
            float deg = 1.0f + (float)wfx_s[t] * (1.0f / FIX_SCALE);
            dinv[node] = rsqrtf(deg);
        }
    }
}

// per bucket: fill CSR epk[pos] = (src, dinv[src]*ew). Destination range
// is the bucket's contiguous ~32KB slice of epk -> block-private, dense.
__global__ __launch_bounds__(256) void k_fill2(const int2* __restrict__ tmp,
                                               const int* __restrict__ bkt_off,
                                               const int* __restrict__ offsets,
                                               const float* __restrict__ dinv,
                                               int2* __restrict__ epk) {
    __shared__ int lcur[BSIZE];
    int t = threadIdx.x;
    int b = blockIdx.x;
    if (t < BSIZE) {
        int node = b * BSIZE + t;
        lcur[t] = (node < N) ? offsets[node] : 0;
    }
    __syncthreads();
    int s0 = bkt_off[b], s1 = bkt_off[b + 1];
    for (int p = s0 + t; p < s1; p += 256) {
        int2 ev = tmp[p];
        unsigned px = (unsigned)ev.x;
        int r = (int)(px & 0x1FFFFu);
        int c7 = (int)(px >> 17);
        float w = __int_as_float(ev.y);
        float nr = dinv[r] * w;
        int pos = atomicAdd(&lcur[c7], 1);
        epk[pos] = make_int2(r, __float_as_int(nr));
    }
}

// --- register-blocked GEMM: H[N,FOUT] = X[N,FIN] @ W[FIN,FOUT] (+b, ELU)
// XMODE: 1 = external input (runtime fp32/bf16 probe), 2 = internal bf16.
// OBF: write bf16 (internal buffer) vs fp32 (final output).
template <int FIN, int FOUT, int TM, int TN, int XMODE, bool OBF, bool BIAS, bool ELU>
__global__ __launch_bounds__(256) void k_gemm(const void* __restrict__ X,
                                              const void* __restrict__ W,
                                              const void* __restrict__ bias,
                                              const int* __restrict__ flags,
                                              void* __restrict__ H) {
    constexpr int TCOLS = FOUT / TN;
    constexpr int TROWS = 256 / TCOLS;
    constexpr int BR = TROWS * TM;
    __shared__ float wl[FIN * FOUT];
    __shared__ float xt[FIN][BR + 1];
    int t = threadIdx.x;
    int isbf = flags[1];
    int base = blockIdx.x * BR;

    if (!isbf) {
        const float4* W4 = (const float4*)W;
        float4* wl4 = (float4*)wl;
        for (int i = t; i < FIN * FOUT / 4; i += 256) wl4[i] = W4[i];
    } else {
        for (int i = t; i < FIN * FOUT; i += 256)
            wl[i] = __bfloat162float(((const __hip_bfloat16*)W)[i]);
    }
    if (XMODE == 2) {
        // internal bf16 buffer: uint2 = 4 bf16
        const uint2* X2 = (const uint2*)X;
        for (int i = t; i < BR * FIN / 4; i += 256) {
            int row = i / (FIN / 4);
            int kq = i % (FIN / 4);
            int node = base + row;
            uint2 u = make_uint2(0u, 0u);
            if (node < N) u = X2[(size_t)node * (FIN / 4) + kq];
            float4 v = bf4tof4(u);
            int k = kq * 4;
            xt[k][row] = v.x; xt[k + 1][row] = v.y;
            xt[k + 2][row] = v.z; xt[k + 3][row] = v.w;
        }
    } else if (!isbf) {
        const float4* X4 = (const float4*)X;
        for (int i = t; i < BR * FIN / 4; i += 256) {
            int row = i / (FIN / 4);
            int kq = i % (FIN / 4);
            int node = base + row;
            float4 v = make_float4(0.f, 0.f, 0.f, 0.f);
            if (node < N) v = X4[(size_t)node * (FIN / 4) + kq];
            int k = kq * 4;
            xt[k][row] = v.x; xt[k + 1][row] = v.y;
            xt[k + 2][row] = v.z; xt[k + 3][row] = v.w;
        }
    } else {
        for (int i = t; i < BR * FIN; i += 256) {
            int row = i / FIN, k = i % FIN;
            int node = base + row;
            float v = (node < N)
                ? __bfloat162float(((const __hip_bfloat16*)X)[(size_t)node * FIN + k]) : 0.f;
            xt[k][row] = v;
        }
    }
    __syncthreads();

    int tcol = t % TCOLS, trow = t / TCOLS;
    int r0 = trow * TM, c0 = tcol * TN;
    float acc[TM][TN] = {};
#pragma unroll 4
    for (int k = 0; k < FIN; k++) {
        float a[TM], b[TN];
#pragma unroll
        for (int m = 0; m < TM; m++) a[m] = xt[k][r0 + m];
#pragma unroll
        for (int n = 0; n < TN; n++) b[n] = wl[k * FOUT + c0 + n];
#pragma unroll
        for (int m = 0; m < TM; m++)
#pragma unroll
            for (int n = 0; n < TN; n++) acc[m][n] += a[m] * b[n];
    }
#pragma unroll
    for (int m = 0; m < TM; m++) {
        int node = base + r0 + m;
        if (node >= N) continue;
        float vv[TN];
#pragma unroll
        for (int n = 0; n < TN; n++) {
            float v = acc[m][n];
            if (BIAS) v += ldf(bias, isbf, c0 + n);
            if (ELU) v = (v > 0.0f) ? v : expm1f(v);
            vv[n] = v;
        }
        if (OBF) {
            unsigned* Hrow = (unsigned*)((unsigned short*)H + (size_t)node * FOUT + c0);
#pragma unroll
            for (int n = 0; n < TN; n += 2)
                Hrow[n / 2] = packbf2(vv[n], vv[n + 1]);
        } else {
            float* Hrow = (float*)H + (size_t)node * FOUT + c0;
#pragma unroll
            for (int n = 0; n < TN; n++) Hrow[n] = vv[n];
        }
    }
}

// --- aggregation: out[n] = di*Σ_e w'_e*H[src_e] + di^2*H[n] (+b, ELU)
// (w' = dinv[src]*ew stored in CSR; dinv[target]=di applied here once)
// Node-parallel, LPN lanes per node, bf16 feature rows (uint2 = 4 bf16
// per lane). Unroll 8 + software pipeline (next 8 epk entries load
// before current gathers are accumulated). fp32 accumulation.
template <int F, bool BIAS, bool ELU>
__global__ __launch_bounds__(256) void k_agg(const uint2* __restrict__ Hb,
                                             const int* __restrict__ offsets,
                                             const int* __restrict__ counts,
                                             const int2* __restrict__ epk,
                                             const float* __restrict__ dinv,
                                             const void* __restrict__ bias,
                                             const int* __restrict__ flags,
                                             uint2* __restrict__ outb) {
    constexpr int LPN = F / 4;        // lanes per node (uint2 per lane)
    constexpr int NPB = 256 / LPN;    // nodes per block
    int t = threadIdx.x;
    int lane = t % LPN;
    int g = t / LPN;
    int node = blockIdx.x * NPB + g;
    if (node >= N) return;
    float di = dinv[node];
    float4 h = bf4tof4(Hb[(size_t)node * LPN + lane]);
    float4 acc0 = make_float4(0.f, 0.f, 0.f, 0.f);
    float4 acc1 = make_float4(0.f, 0.f, 0.f, 0.f);
    int p = offsets[node];
    int pend = p + counts[node];

    int2 eA[8];
    bool have = (p + 8 <= pend);
    if (have) {
#pragma unroll
        for (int j = 0; j < 8; j++) eA[j] = epk[p + j];
    }
    while (have) {
        // issue 8 independent gathers (8B each)
        uint2 gg[8];
#pragma unroll
        for (int j = 0; j < 8; j++)
            gg[j] = Hb[(size_t)eA[j].x * LPN + lane];
        float w[8];
#pragma unroll
        for (int j = 0; j < 8; j++) w[j] = __int_as_float(eA[j].y);
        p += 8;
        bool nxt = (p + 8 <= pend);
        int2 eB[8];
        if (nxt) {
#pragma unroll
            for (int j = 0; j < 8; j++) eB[j] = epk[p + j];
        }
        // accumulate current batch (drains gather vmcnt; next epk loads
        // already in flight)
#pragma unroll
        for (int j = 0; j < 8; j += 2) {
            float4 g0 = bf4tof4(gg[j]);
            float4 g1 = bf4tof4(gg[j + 1]);
            acc0.x += g0.x * w[j]; acc0.y += g0.y * w[j];
            acc0.z += g0.z * w[j]; acc0.w += g0.w * w[j];
            acc1.x += g1.x * w[j + 1]; acc1.y += g1.y * w[j + 1];
            acc1.z += g1.z * w[j + 1]; acc1.w += g1.w * w[j + 1];
        }
#pragma unroll
        for (int j = 0; j < 8; j++) eA[j] = eB[j];
        have = nxt;
    }
    // tail: 4-wide then scalar
    for (; p + 4 <= pend; p += 4) {
        int2 e0 = epk[p], e1 = epk[p + 1], e2 = epk[p + 2], e3 = epk[p + 3];
        float4 h0 = bf4tof4(Hb[(size_t)e0.x * LPN + lane]);
        float4 h1 = bf4tof4(Hb[(size_t)e1.x * LPN + lane]);
        float4 h2 = bf4tof4(Hb[(size_t)e2.x * LPN + lane]);
        float4 h3 = bf4tof4(Hb[(size_t)e3.x * LPN + lane]);
        float w0 = __int_as_float(e0.y), w1 = __int_as_float(e1.y);
        float w2 = __int_as_float(e2.y), w3 = __int_as_float(e3.y);
        acc0.x += h0.x * w0 + h2.x * w2; acc1.x += h1.x * w1 + h3.x * w3;
        acc0.y += h0.y * w0 + h2.y * w2; acc1.y += h1.y * w1 + h3.y * w3;
        acc0.z += h0.z * w0 + h2.z * w2; acc1.z += h1.z * w1 + h3.z * w3;
        acc0.w += h0.w * w0 + h2.w * w2; acc1.w += h1.w * w1 + h3.w * w3;
    }
    for (; p < pend; p++) {
        int2 e = epk[p];
        float4 hh = bf4tof4(Hb[(size_t)e.x * LPN + lane]);
        float w = __int_as_float(e.y);
        acc0.x += hh.x * w; acc0.y += hh.y * w;
        acc0.z += hh.z * w; acc0.w += hh.w * w;
    }
    float4 acc;
    acc.x = acc0.x + acc1.x; acc.y = acc0.y + acc1.y;
    acc.z = acc0.z + acc1.z; acc.w = acc0.w + acc1.w;
    float sw = di * di;
    acc.x = acc.x * di + h.x * sw;
    acc.y = acc.y * di + h.y * sw;
    acc.z = acc.z * di + h.z * sw;
    acc.w = acc.w * di + h.w * sw;
    if (BIAS) {
        int fb = lane * 4;
        int isbf = flags[1];
        acc.x += ldf(bias, isbf, fb);
        acc.y += ldf(bias, isbf, fb + 1);
        acc.z += ldf(bias, isbf, fb + 2);
        acc.w += ldf(bias, isbf, fb + 3);
    }
    if (ELU) {
        acc.x = (acc.x > 0.0f) ? acc.x : expm1f(acc.x);
        acc.y = (acc.y > 0.0f) ? acc.y : expm1f(acc.y);
        acc.z = (acc.z > 0.0f) ? acc.z : expm1f(acc.z);
        acc.w = (acc.w > 0.0f) ? acc.w : expm1f(acc.w);
    }
    outb[(size_t)node * LPN + lane] = f4tobf4(acc);
}

// diagnostic fallback: if ws_size too small, emit sentinel 123.0
__global__ void k_sentinel(float* out, int n) {
    int i = blockIdx.x * blockDim.x + threadIdx.x;
    if (i < n) out[i] = 123.0f;
}

extern "C" void kernel_launch(void* const* d_in, const int* in_sizes, int n_in,
                              void* d_out, int out_size, void* d_ws, size_t ws_size,
                              hipStream_t stream) {
    const void* x  = d_in[0];
    const void* ei = d_in[1];
    const void* ea = d_in[2];
    const void* W1 = d_in[3];
    const void* b1 = d_in[4];
    const void* W2 = d_in[5];
    const void* b2 = d_in[6];
    const void* W3 = d_in[7];
    const void* b3 = d_in[8];
    float* out = (float*)d_out;

    // workspace layout (256B aligned)
    char* ws = (char*)d_ws;
    size_t off = 0;
    auto alloc = [&](size_t bytes) {
        off = (off + 255) & ~(size_t)255;
        size_t r = off;
        off += bytes;
        return r;
    };
    float* dinv    = (float*)(ws + alloc((size_t)N * 4));
    int*   counts  = (int*)  (ws + alloc((size_t)N * 4));
    int*   offsets = (int*)  (ws + alloc((size_t)N * 4));
    int*   bkt_cnt = (int*)  (ws + alloc((size_t)NBKT * 4));
    int*   bkt_off = (int*)  (ws + alloc((size_t)(NBKT + 1) * 4));
    int*   bkt_cur = (int*)  (ws + alloc((size_t)NBKT * 4));
    int*   flags   = (int*)  (ws + alloc(256));
    int2*  epk     = (int2*) (ws + alloc((size_t)E * 8));
    // bf16 feature buffers: N*64*2 = 12.8MB each; allocated back-to-back
    // (12.8MB is 256B-aligned) so tmp (E*8 = 25.6MB) aliases bufA+bufB.
    // tmp's last read (k_fill2) precedes bufA's first write (L1 GEMM).
    unsigned short* bufA = (unsigned short*)(ws + alloc((size_t)N * 64 * 2));
    unsigned short* bufB = (unsigned short*)(ws + alloc((size_t)N * 64 * 2));
    size_t need = off;
    int2* tmp = (int2*)bufA;

    if (ws_size < need) {
        hipLaunchKernelGGL(k_sentinel, dim3((N * 128 + 255) / 256), dim3(256), 0, stream,
                           out, N * 128);
        return;
    }

    const int gH = (E + HIST_EPB - 1) / HIST_EPB;   // 391
    const int gS = (E + SC_EPB - 1) / SC_EPB;       // 196

    hipLaunchKernelGGL(k_probe, dim3(1), dim3(256), 0, stream, ei, x, flags, bkt_cnt);
    hipLaunchKernelGGL(k_hist, dim3(gH), dim3(256), 0, stream, ei, flags, bkt_cnt);
    hipLaunchKernelGGL(k_bscan, dim3(1), dim3(256), 0, stream, bkt_cnt, bkt_off, bkt_cur);
    hipLaunchKernelGGL(k_scatter, dim3(gS), dim3(256), 0, stream, ei, flags, ea, bkt_cur, tmp);
    hipLaunchKernelGGL(k_nodecnt, dim3(NBKT), dim3(256), 0, stream, tmp, bkt_off,
                       counts, offsets, dinv);
    hipLaunchKernelGGL(k_fill2, dim3(NBKT), dim3(256), 0, stream, tmp, bkt_off,
                       offsets, dinv, epk);

    // L1: t1 = x@W1 (bufA, F=32 bf16); a1 = ELU(agg(t1)+b1) (bufB bf16)
    hipLaunchKernelGGL((k_gemm<128, 32, 2, 4, 1, true, false, false>),
                       dim3((N + 63) / 64), dim3(256), 0, stream, x, W1, nullptr, flags, bufA);
    hipLaunchKernelGGL((k_agg<32, true, true>), dim3((N + 31) / 32), dim3(256), 0, stream,
                       (const uint2*)bufA, offsets, counts, epk, dinv, b1, flags, (uint2*)bufB);
    // L2: s2 = agg(a1) (bufA bf16); h2 = ELU(s2@W2+b2) (bufB, F=64 bf16)
    hipLaunchKernelGGL((k_agg<32, false, false>), dim3((N + 31) / 32), dim3(256), 0, stream,
                       (const uint2*)bufB, offsets, counts, epk, dinv, nullptr, flags, (uint2*)bufA);
    hipLaunchKernelGGL((k_gemm<32, 64, 4, 4, 2, true, true, true>),
                       dim3((N + 63) / 64), dim3(256), 0, stream, bufA, W2, b2, flags, bufB);
    // L3: s3 = agg(h2) (bufA, F=64 bf16); out = s3@W3+b3 (d_out fp32)
    hipLaunchKernelGGL((k_agg<64, false, false>), dim3((N + 15) / 16), dim3(256), 0, stream,
                       (const uint2*)bufB, offsets, counts, epk, dinv, nullptr, flags, (uint2*)bufA);
    hipLaunchKernelGGL((k_gemm<64, 128, 4, 8, 2, false, true, false>),
                       dim3((N + 63) / 64), dim3(256), 0, stream, bufA, W3, b3, flags, out);
}

// Round 5
// 498.347 us; speedup vs baseline: 6.0551x; 1.0212x over previous
//
#include <hip/hip_runtime.h>
#include <hip/hip_bf16.h>

// GCN 3-layer: gcn_norm -> (GCNConv, ELU) x2 -> GCNConv
// N=100000, E=3200000, dims 128->32->64->128.
// agg is linear => aggregate in the SMALLER feature dim per layer:
//   L1: t1 = x@W1 (128->32); a1 = ELU(agg(t1) + b1)          [gather F=32]
//   L2: s2 = agg(a1);        h2 = ELU(s2@W2 + b2)            [gather F=32]
//   L3: s3 = agg(h2);        out = s3@W3 + b3                [gather F=64]
//
// CSR build: bucketed 2-level counting sort (k_hist -> k_bscan ->
// k_scatter -> k_nodecnt -> k_fill2); epk holds (src, dinv[src]*ew).
//
// LESSONS:
//  - r2: LDS f32 atomicAdd agg = 12x slower (ds_add_f32 ~0.25 ops/cy/CU).
//  - r3: agg is near the compulsory-traffic ceiling for random gathers;
//    latency engineering bought 7%. Bytes are the lever.
//  - r4: bf16 intermediate buffers (storage only, fp32 accum) -> -93us.
//  - r5 (this): k_scatter was occupancy-starved: 196 blocks x 256thr =
//    4 waves/CU (7.5% occ, VALU 2%, BW 13%) -> every LDS-atomic/global
//    latency exposed. Now 391 blocks x 512 threads (EPB 8192) = ~12
//    waves/CU; k_hist likewise. Atomic reservations 153K->306K (cheap).
// GEMMs register-blocked 64-row tiles. Inputs: fp32 (probed vs bf16),
// edge_index i64 (probed vs i32). Output fp32.

constexpr int N = 100000;
constexpr int E = 3200000;

constexpr int BSHIFT = 7;
constexpr int BSIZE = 128;                       // nodes per bucket
constexpr int NBKT = (N + BSIZE - 1) / BSIZE;    // 782

constexpr float FIX_SCALE = 16777216.0f;         // 2^24

constexpr int HIST_EPB = 8192;                   // edges per block, hist
constexpr int SC_EPB = 8192;                     // edges per block, scatter

__device__ __forceinline__ float ldf(const void* p, int isbf, size_t i) {
    return isbf ? __bfloat162float(((const __hip_bfloat16*)p)[i])
                : ((const float*)p)[i];
}

__device__ __forceinline__ int ld_idx(const void* ei, int is64, size_t pos) {
    return is64 ? (int)((const long long*)ei)[pos] : ((const int*)ei)[pos];
}

// --- bf16x4 pack/unpack (manual RNE, no API dependence) ---
__device__ __forceinline__ float4 bf4tof4(uint2 u) {
    float4 r;
    r.x = __uint_as_float(u.x << 16);
    r.y = __uint_as_float(u.x & 0xffff0000u);
    r.z = __uint_as_float(u.y << 16);
    r.w = __uint_as_float(u.y & 0xffff0000u);
    return r;
}
__device__ __forceinline__ unsigned short f2bf(float f) {
    unsigned u = __float_as_uint(f);
    unsigned rnd = 0x7fffu + ((u >> 16) & 1u);
    return (unsigned short)((u + rnd) >> 16);
}
__device__ __forceinline__ unsigned packbf2(float a, float b) {
    return (unsigned)f2bf(a) | ((unsigned)f2bf(b) << 16);
}
__device__ __forceinline__ uint2 f4tobf4(float4 v) {
    uint2 r;
    r.x = packbf2(v.x, v.y);
    r.y = packbf2(v.z, v.w);
    return r;
}

// flags[0] = is64 (edge_index), flags[1] = isbf (float tensors)
// also zeroes the bucket-count array (runs before k_hist on the stream)
__global__ void k_probe(const void* ei, const void* x, int* flags, int* bkt_cnt) {
    __shared__ int bad64, bigcnt;
    int t = threadIdx.x;
    if (t == 0) { bad64 = 0; bigcnt = 0; }
    __syncthreads();
    long long v = ((const long long*)ei)[t];
    if (v < 0 || v >= (long long)N) atomicAdd(&bad64, 1);
    const unsigned short* u = (const unsigned short*)x;
    int big = 0;
    for (int i = t * 16; i < t * 16 + 16; i++) {
        int e = (u[i] >> 7) & 0xFF;
        if (e >= 133) big++;
    }
    atomicAdd(&bigcnt, big);
    for (int i = t; i < NBKT; i += 256) bkt_cnt[i] = 0;
    __syncthreads();
    if (t == 0) { flags[0] = (bad64 == 0) ? 1 : 0; flags[1] = (bigcnt < 40) ? 1 : 0; }
}

// bucket histogram: LDS per block, one global atomic per (block,bucket)
__global__ __launch_bounds__(512) void k_hist(const void* ei, const int* flags,
                                              int* bkt_cnt) {
    __shared__ int h[NBKT];
    int t = threadIdx.x;
    for (int i = t; i < NBKT; i += 512) h[i] = 0;
    __syncthreads();
    int is64 = flags[0];
    size_t eb = (size_t)blockIdx.x * HIST_EPB;
    int nb = (int)min((size_t)HIST_EPB, (size_t)E - eb);
    for (int k = t; k < nb; k += 512) {
        int c = ld_idx(ei, is64, (size_t)E + eb + k);
        atomicAdd(&h[c >> BSHIFT], 1);
    }
    __syncthreads();
    for (int i = t; i < NBKT; i += 512) {
        int v = h[i];
        if (v) atomicAdd(&bkt_cnt[i], v);
    }
}

// single-block exclusive scan over NBKT buckets -> bkt_off, bkt_cur
__global__ void k_bscan(const int* bkt_cnt, int* bkt_off, int* bkt_cur) {
    __shared__ int s[256];
    int t = threadIdx.x;
    int v[4]; int sum = 0;
#pragma unroll
    for (int j = 0; j < 4; j++) {
        int i = t * 4 + j;
        v[j] = (i < NBKT) ? bkt_cnt[i] : 0;
        sum += v[j];
    }
    s[t] = sum; __syncthreads();
    for (int st = 1; st < 256; st <<= 1) {
        int add = (t >= st) ? s[t - st] : 0;
        __syncthreads();
        s[t] += add;
        __syncthreads();
    }
    int excl = s[t] - sum;
#pragma unroll
    for (int j = 0; j < 4; j++) {
        int i = t * 4 + j;
        if (i < NBKT) { bkt_off[i] = excl; bkt_cur[i] = excl; excl += v[j]; }
    }
    if (t == 0) bkt_off[NBKT] = E;
}

// bucket-sort edges into tmp[]: per-block LDS histogram, one run
// reservation atomic per (block,bucket), dense run writes.
// tmp entry: .x = r | (c&127)<<17  (r<2^17, fits), .y = w bits
__global__ __launch_bounds__(512) void k_scatter(const void* ei, const int* flags,
                                                 const void* ew, int* bkt_cur,
                                                 int2* tmp) {
    __shared__ int h[NBKT];
    __shared__ int base_s[NBKT];
    int t = threadIdx.x;
    for (int i = t; i < NBKT; i += 512) h[i] = 0;
    __syncthreads();
    int is64 = flags[0], isbf = flags[1];
    size_t eb = (size_t)blockIdx.x * SC_EPB;
    int nb = (int)min((size_t)SC_EPB, (size_t)E - eb);
    // pass 1: local histogram
    for (int k = t; k < nb; k += 512) {
        int c = ld_idx(ei, is64, (size_t)E + eb + k);
        atomicAdd(&h[c >> BSHIFT], 1);
    }
    __syncthreads();
    // reserve a dense run per bucket
    for (int i = t; i < NBKT; i += 512) {
        int v = h[i];
        base_s[i] = v ? atomicAdd(&bkt_cur[i], v) : 0;
    }
    __syncthreads();
    for (int i = t; i < NBKT; i += 512) h[i] = 0;
    __syncthreads();
    // pass 2: place edges within reserved runs
    for (int k = t; k < nb; k += 512) {
        size_t e = eb + k;
        int r = ld_idx(ei, is64, e);
        int c = ld_idx(ei, is64, (size_t)E + e);
        float w = ldf(ew, isbf, e);
        int b = c >> BSHIFT;
        int loc = atomicAdd(&h[b], 1);
        int pos = base_s[b] + loc;
        tmp[pos] = make_int2(r | ((c & (BSIZE - 1)) << 17), __float_as_int(w));
    }
}

// per bucket: node counts + fixed-point weight sums (LDS int atomics,
// cheap at this scale), 128-wide LDS scan -> offsets;
// dinv = rsqrt(1 + wsum) (bit-identical to the original packed scheme)
__global__ __launch_bounds__(256) void k_nodecnt(const int2* __restrict__ tmp,
                                                 const int* __restrict__ bkt_off,
                                                 int* __restrict__ counts,
                                                 int* __restrict__ offsets,
                                                 float* __restrict__ dinv) {
    __shared__ int cnt_s[BSIZE];
    __shared__ unsigned int wfx_s[BSIZE];
    __shared__ int sc_s[BSIZE];
    int t = threadIdx.x;
    int b = blockIdx.x;
    if (t < BSIZE) { cnt_s[t] = 0; wfx_s[t] = 0u; }
    __syncthreads();
    int s0 = bkt_off[b], s1 = bkt_off[b + 1];
    for (int p = s0 + t; p < s1; p += 256) {
        int2 ev = tmp[p];
        int c7 = (int)(((unsigned)ev.x) >> 17);
        float w = __int_as_float(ev.y);
        atomicAdd(&cnt_s[c7], 1);
        atomicAdd(&wfx_s[c7], (unsigned)__float2uint_rn(w * FIX_SCALE));
    }
    __syncthreads();
    if (t < BSIZE) sc_s[t] = cnt_s[t];
    __syncthreads();
    for (int st = 1; st < BSIZE; st <<= 1) {
        int add = (t < BSIZE && t >= st) ? sc_s[t - st] : 0;
        __syncthreads();
        if (t < BSIZE) sc_s[t] += add;
        __syncthreads();
    }
    if (t < BSIZE) {
        int node = b * BSIZE + t;
        if (node < N) {
            int c = cnt_s[t];
            offsets[node] = s0 + sc_s[t] - c;   // bucket base + exclusive
            counts[node] = c;
            float deg = 1.0f + (float)wfx_s[t] * (1.0f / FIX_SCALE);
            dinv[node] = rsqrtf(deg);
        }
    }
}

// per bucket: fill CSR epk[pos] = (src, dinv[src]*ew). Destination range
// is the bucket's contiguous ~32KB slice of epk -> block-private, dense.
__global__ __launch_bounds__(256) void k_fill2(const int2* __restrict__ tmp,
                                               const int* __restrict__ bkt_off,
                                               const int* __restrict__ offsets,
                                               const float* __restrict__ dinv,
                                               int2* __restrict__ epk) {
    __shared__ int lcur[BSIZE];
    int t = threadIdx.x;
    int b = blockIdx.x;
    if (t < BSIZE) {
        int node = b * BSIZE + t;
        lcur[t] = (node < N) ? offsets[node] : 0;
    }
    __syncthreads();
    int s0 = bkt_off[b], s1 = bkt_off[b + 1];
    for (int p = s0 + t; p < s1; p += 256) {
        int2 ev = tmp[p];
        unsigned px = (unsigned)ev.x;
        int r = (int)(px & 0x1FFFFu);
        int c7 = (int)(px >> 17);
        float w = __int_as_float(ev.y);
        float nr = dinv[r] * w;
        int pos = atomicAdd(&lcur[c7], 1);
        epk[pos] = make_int2(r, __float_as_int(nr));
    }
}

// --- register-blocked GEMM: H[N,FOUT] = X[N,FIN] @ W[FIN,FOUT] (+b, ELU)
// XMODE: 1 = external input (runtime fp32/bf16 probe), 2 = internal bf16.
// OBF: write bf16 (internal buffer) vs fp32 (final output).
template <int FIN, int FOUT, int TM, int TN, int XMODE, bool OBF, bool BIAS, bool ELU>
__global__ __launch_bounds__(256) void k_gemm(const void* __restrict__ X,
                                              const void* __restrict__ W,
                                              const void* __restrict__ bias,
                                              const int* __restrict__ flags,
                                              void* __restrict__ H) {
    constexpr int TCOLS = FOUT / TN;
    constexpr int TROWS = 256 / TCOLS;
    constexpr int BR = TROWS * TM;
    __shared__ float wl[FIN * FOUT];
    __shared__ float xt[FIN][BR + 1];
    int t = threadIdx.x;
    int isbf = flags[1];
    int base = blockIdx.x * BR;

    if (!isbf) {
        const float4* W4 = (const float4*)W;
        float4* wl4 = (float4*)wl;
        for (int i = t; i < FIN * FOUT / 4; i += 256) wl4[i] = W4[i];
    } else {
        for (int i = t; i < FIN * FOUT; i += 256)
            wl[i] = __bfloat162float(((const __hip_bfloat16*)W)[i]);
    }
    if (XMODE == 2) {
        // internal bf16 buffer: uint2 = 4 bf16
        const uint2* X2 = (const uint2*)X;
        for (int i = t; i < BR * FIN / 4; i += 256) {
            int row = i / (FIN / 4);
            int kq = i % (FIN / 4);
            int node = base + row;
            uint2 u = make_uint2(0u, 0u);
            if (node < N) u = X2[(size_t)node * (FIN / 4) + kq];
            float4 v = bf4tof4(u);
            int k = kq * 4;
            xt[k][row] = v.x; xt[k + 1][row] = v.y;
            xt[k + 2][row] = v.z; xt[k + 3][row] = v.w;
        }
    } else if (!isbf) {
        const float4* X4 = (const float4*)X;
        for (int i = t; i < BR * FIN / 4; i += 256) {
            int row = i / (FIN / 4);
            int kq = i % (FIN / 4);
            int node = base + row;
            float4 v = make_float4(0.f, 0.f, 0.f, 0.f);
            if (node < N) v = X4[(size_t)node * (FIN / 4) + kq];
            int k = kq * 4;
            xt[k][row] = v.x; xt[k + 1][row] = v.y;
            xt[k + 2][row] = v.z; xt[k + 3][row] = v.w;
        }
    } else {
        for (int i = t; i < BR * FIN; i += 256) {
            int row = i / FIN, k = i % FIN;
            int node = base + row;
            float v = (node < N)
                ? __bfloat162float(((const __hip_bfloat16*)X)[(size_t)node * FIN + k]) : 0.f;
            xt[k][row] = v;
        }
    }
    __syncthreads();

    int tcol = t % TCOLS, trow = t / TCOLS;
    int r0 = trow * TM, c0 = tcol * TN;
    float acc[TM][TN] = {};
#pragma unroll 4
    for (int k = 0; k < FIN; k++) {
        float a[TM], b[TN];
#pragma unroll
        for (int m = 0; m < TM; m++) a[m] = xt[k][r0 + m];
#pragma unroll
        for (int n = 0; n < TN; n++) b[n] = wl[k * FOUT + c0 + n];
#pragma unroll
        for (int m = 0; m < TM; m++)
#pragma unroll
            for (int n = 0; n < TN; n++) acc[m][n] += a[m] * b[n];
    }
#pragma unroll
    for (int m = 0; m < TM; m++) {
        int node = base + r0 + m;
        if (node >= N) continue;
        float vv[TN];
#pragma unroll
        for (int n = 0; n < TN; n++) {
            float v = acc[m][n];
            if (BIAS) v += ldf(bias, isbf, c0 + n);
            if (ELU) v = (v > 0.0f) ? v : expm1f(v);
            vv[n] = v;
        }
        if (OBF) {
            unsigned* Hrow = (unsigned*)((unsigned short*)H + (size_t)node * FOUT + c0);
#pragma unroll
            for (int n = 0; n < TN; n += 2)
                Hrow[n / 2] = packbf2(vv[n], vv[n + 1]);
        } else {
            float* Hrow = (float*)H + (size_t)node * FOUT + c0;
#pragma unroll
            for (int n = 0; n < TN; n++) Hrow[n] = vv[n];
        }
    }
}

// --- aggregation: out[n] = di*Σ_e w'_e*H[src_e] + di^2*H[n] (+b, ELU)
// (w' = dinv[src]*ew stored in CSR; dinv[target]=di applied here once)
// Node-parallel, LPN lanes per node, bf16 feature rows (uint2 = 4 bf16
// per lane). Unroll 8 + software pipeline (next 8 epk entries load
// before current gathers are accumulated). fp32 accumulation.
template <int F, bool BIAS, bool ELU>
__global__ __launch_bounds__(256) void k_agg(const uint2* __restrict__ Hb,
                                             const int* __restrict__ offsets,
                                             const int* __restrict__ counts,
                                             const int2* __restrict__ epk,
                                             const float* __restrict__ dinv,
                                             const void* __restrict__ bias,
                                             const int* __restrict__ flags,
                                             uint2* __restrict__ outb) {
    constexpr int LPN = F / 4;        // lanes per node (uint2 per lane)
    constexpr int NPB = 256 / LPN;    // nodes per block
    int t = threadIdx.x;
    int lane = t % LPN;
    int g = t / LPN;
    int node = blockIdx.x * NPB + g;
    if (node >= N) return;
    float di = dinv[node];
    float4 h = bf4tof4(Hb[(size_t)node * LPN + lane]);
    float4 acc0 = make_float4(0.f, 0.f, 0.f, 0.f);
    float4 acc1 = make_float4(0.f, 0.f, 0.f, 0.f);
    int p = offsets[node];
    int pend = p + counts[node];

    int2 eA[8];
    bool have = (p + 8 <= pend);
    if (have) {
#pragma unroll
        for (int j = 0; j < 8; j++) eA[j] = epk[p + j];
    }
    while (have) {
        // issue 8 independent gathers (8B each)
        uint2 gg[8];
#pragma unroll
        for (int j = 0; j < 8; j++)
            gg[j] = Hb[(size_t)eA[j].x * LPN + lane];
        float w[8];
#pragma unroll
        for (int j = 0; j < 8; j++) w[j] = __int_as_float(eA[j].y);
        p += 8;
        bool nxt = (p + 8 <= pend);
        int2 eB[8];
        if (nxt) {
#pragma unroll
            for (int j = 0; j < 8; j++) eB[j] = epk[p + j];
        }
        // accumulate current batch (drains gather vmcnt; next epk loads
        // already in flight)
#pragma unroll
        for (int j = 0; j < 8; j += 2) {
            float4 g0 = bf4tof4(gg[j]);
            float4 g1 = bf4tof4(gg[j + 1]);
            acc0.x += g0.x * w[j]; acc0.y += g0.y * w[j];
            acc0.z += g0.z * w[j]; acc0.w += g0.w * w[j];
            acc1.x += g1.x * w[j + 1]; acc1.y += g1.y * w[j + 1];
            acc1.z += g1.z * w[j + 1]; acc1.w += g1.w * w[j + 1];
        }
#pragma unroll
        for (int j = 0; j < 8; j++) eA[j] = eB[j];
        have = nxt;
    }
    // tail: 4-wide then scalar
    for (; p + 4 <= pend; p += 4) {
        int2 e0 = epk[p], e1 = epk[p + 1], e2 = epk[p + 2], e3 = epk[p + 3];
        float4 h0 = bf4tof4(Hb[(size_t)e0.x * LPN + lane]);
        float4 h1 = bf4tof4(Hb[(size_t)e1.x * LPN + lane]);
        float4 h2 = bf4tof4(Hb[(size_t)e2.x * LPN + lane]);
        float4 h3 = bf4tof4(Hb[(size_t)e3.x * LPN + lane]);
        float w0 = __int_as_float(e0.y), w1 = __int_as_float(e1.y);
        float w2 = __int_as_float(e2.y), w3 = __int_as_float(e3.y);
        acc0.x += h0.x * w0 + h2.x * w2; acc1.x += h1.x * w1 + h3.x * w3;
        acc0.y += h0.y * w0 + h2.y * w2; acc1.y += h1.y * w1 + h3.y * w3;
        acc0.z += h0.z * w0 + h2.z * w2; acc1.z += h1.z * w1 + h3.z * w3;
        acc0.w += h0.w * w0 + h2.w * w2; acc1.w += h1.w * w1 + h3.w * w3;
    }
    for (; p < pend; p++) {
        int2 e = epk[p];
        float4 hh = bf4tof4(Hb[(size_t)e.x * LPN + lane]);
        float w = __int_as_float(e.y);
        acc0.x += hh.x * w; acc0.y += hh.y * w;
        acc0.z += hh.z * w; acc0.w += hh.w * w;
    }
    float4 acc;
    acc.x = acc0.x + acc1.x; acc.y = acc0.y + acc1.y;
    acc.z = acc0.z + acc1.z; acc.w = acc0.w + acc1.w;
    float sw = di * di;
    acc.x = acc.x * di + h.x * sw;
    acc.y = acc.y * di + h.y * sw;
    acc.z = acc.z * di + h.z * sw;
    acc.w = acc.w * di + h.w * sw;
    if (BIAS) {
        int fb = lane * 4;
        int isbf = flags[1];
        acc.x += ldf(bias, isbf, fb);
        acc.y += ldf(bias, isbf, fb + 1);
        acc.z += ldf(bias, isbf, fb + 2);
        acc.w += ldf(bias, isbf, fb + 3);
    }
    if (ELU) {
        acc.x = (acc.x > 0.0f) ? acc.x : expm1f(acc.x);
        acc.y = (acc.y > 0.0f) ? acc.y : expm1f(acc.y);
        acc.z = (acc.z > 0.0f) ? acc.z : expm1f(acc.z);
        acc.w = (acc.w > 0.0f) ? acc.w : expm1f(acc.w);
    }
    outb[(size_t)node * LPN + lane] = f4tobf4(acc);
}

// diagnostic fallback: if ws_size too small, emit sentinel 123.0
__global__ void k_sentinel(float* out, int n) {
    int i = blockIdx.x * blockDim.x + threadIdx.x;
    if (i < n) out[i] = 123.0f;
}

extern "C" void kernel_launch(void* const* d_in, const int* in_sizes, int n_in,
                              void* d_out, int out_size, void* d_ws, size_t ws_size,
                              hipStream_t stream) {
    const void* x  = d_in[0];
    const void* ei = d_in[1];
    const void* ea = d_in[2];
    const void* W1 = d_in[3];
    const void* b1 = d_in[4];
    const void* W2 = d_in[5];
    const void* b2 = d_in[6];
    const void* W3 = d_in[7];
    const void* b3 = d_in[8];
    float* out = (float*)d_out;

    // workspace layout (256B aligned)
    char* ws = (char*)d_ws;
    size_t off = 0;
    auto alloc = [&](size_t bytes) {
        off = (off + 255) & ~(size_t)255;
        size_t r = off;
        off += bytes;
        return r;
    };
    float* dinv    = (float*)(ws + alloc((size_t)N * 4));
    int*   counts  = (int*)  (ws + alloc((size_t)N * 4));
    int*   offsets = (int*)  (ws + alloc((size_t)N * 4));
    int*   bkt_cnt = (int*)  (ws + alloc((size_t)NBKT * 4));
    int*   bkt_off = (int*)  (ws + alloc((size_t)(NBKT + 1) * 4));
    int*   bkt_cur = (int*)  (ws + alloc((size_t)NBKT * 4));
    int*   flags   = (int*)  (ws + alloc(256));
    int2*  epk     = (int2*) (ws + alloc((size_t)E * 8));
    // bf16 feature buffers: N*64*2 = 12.8MB each; allocated back-to-back
    // (12.8MB is 256B-aligned) so tmp (E*8 = 25.6MB) aliases bufA+bufB.
    // tmp's last read (k_fill2) precedes bufA's first write (L1 GEMM).
    unsigned short* bufA = (unsigned short*)(ws + alloc((size_t)N * 64 * 2));
    unsigned short* bufB = (unsigned short*)(ws + alloc((size_t)N * 64 * 2));
    size_t need = off;
    int2* tmp = (int2*)bufA;

    if (ws_size < need) {
        hipLaunchKernelGGL(k_sentinel, dim3((N * 128 + 255) / 256), dim3(256), 0, stream,
                           out, N * 128);
        return;
    }

    const int gH = (E + HIST_EPB - 1) / HIST_EPB;   // 391
    const int gS = (E + SC_EPB - 1) / SC_EPB;       // 391

    hipLaunchKernelGGL(k_probe, dim3(1), dim3(256), 0, stream, ei, x, flags, bkt_cnt);
    hipLaunchKernelGGL(k_hist, dim3(gH), dim3(512), 0, stream, ei, flags, bkt_cnt);
    hipLaunchKernelGGL(k_bscan, dim3(1), dim3(256), 0, stream, bkt_cnt, bkt_off, bkt_cur);
    hipLaunchKernelGGL(k_scatter, dim3(gS), dim3(512), 0, stream, ei, flags, ea, bkt_cur, tmp);
    hipLaunchKernelGGL(k_nodecnt, dim3(NBKT), dim3(256), 0, stream, tmp, bkt_off,
                       counts, offsets, dinv);
    hipLaunchKernelGGL(k_fill2, dim3(NBKT), dim3(256), 0, stream, tmp, bkt_off,
                       offsets, dinv, epk);

    // L1: t1 = x@W1 (bufA, F=32 bf16); a1 = ELU(agg(t1)+b1) (bufB bf16)
    hipLaunchKernelGGL((k_gemm<128, 32, 2, 4, 1, true, false, false>),
                       dim3((N + 63) / 64), dim3(256), 0, stream, x, W1, nullptr, flags, bufA);
    hipLaunchKernelGGL((k_agg<32, true, true>), dim3((N + 31) / 32), dim3(256), 0, stream,
                       (const uint2*)bufA, offsets, counts, epk, dinv, b1, flags, (uint2*)bufB);
    // L2: s2 = agg(a1) (bufA bf16); h2 = ELU(s2@W2+b2) (bufB, F=64 bf16)
    hipLaunchKernelGGL((k_agg<32, false, false>), dim3((N + 31) / 32), dim3(256), 0, stream,
                       (const uint2*)bufB, offsets, counts, epk, dinv, nullptr, flags, (uint2*)bufA);
    hipLaunchKernelGGL((k_gemm<32, 64, 4, 4, 2, true, true, true>),
                       dim3((N + 63) / 64), dim3(256), 0, stream, bufA, W2, b2, flags, bufB);
    // L3: s3 = agg(h2) (bufA, F=64 bf16); out = s3@W3+b3 (d_out fp32)
    hipLaunchKernelGGL((k_agg<64, false, false>), dim3((N + 15) / 16), dim3(256), 0, stream,
                       (const uint2*)bufB, offsets, counts, epk, dinv, nullptr, flags, (uint2*)bufA);
    hipLaunchKernelGGL((k_gemm<64, 128, 4, 8, 2, false, true, false>),
                       dim3((N + 63) / 64), dim3(256), 0, stream, bufA, W3, b3, flags, out);
}

// Round 7
// 464.076 us; speedup vs baseline: 6.5023x; 1.0738x over previous
//
#include <hip/hip_runtime.h>
#include <hip/hip_bf16.h>

// GCN 3-layer: gcn_norm -> (GCNConv, ELU) x2 -> GCNConv
// N=100000, E=3200000, dims 128->32->64->128.
// agg is linear => aggregate in the SMALLER feature dim per layer:
//   L1: t1 = x@W1 (128->32); a1 = ELU(agg(t1) + b1)          [gather F=32]
//   L2: s2 = agg(a1);        h2 = ELU(s2@W2 + b2)            [gather F=32]
//   L3: s3 = agg(h2);        out = s3@W3 + b3                [gather F=64]
//
// CSR build: bucketed 2-level counting sort (k_hist -> k_bscan ->
// k_scatter -> k_nodecnt -> k_fill2); epk holds (src, dinv[src]*ew).
//
// LESSONS:
//  - r2: LDS f32 atomicAdd agg = 12x slower (ds_add_f32 ~0.25 ops/cy/CU).
//  - r3: agg is near the compulsory-traffic ceiling for random gathers;
//    latency engineering bought 7%. Bytes are the lever.
//  - r4: bf16 intermediate buffers (storage only, fp32 accum) -> -93us.
//  - r5: scatter occupancy 7.5->23.5% bought only 15%: waves weren't
//    the serializer. Real chain: per-iteration load->LDS-atomic->store
//    dependence + 391 blocks on 256 CUs (2-block CUs set the time).
//  - r6: batch-load-then-process: each thread loads ALL its (r,c,w)
//    into registers first (independent coalesced loads, one drain),
//    then runs both histogram and placement passes from registers --
//    second ei read deleted, no load behind an atomic. EPB 4096 ->
//    782 blocks = 3.05/CU uniform balance. k_hist same.
//    (r6 bench was an infra failure -- resubmitted unchanged.)
// GEMMs register-blocked 64-row tiles. Inputs: fp32 (probed vs bf16),
// edge_index i64 (probed vs i32). Output fp32.

constexpr int N = 100000;
constexpr int E = 3200000;

constexpr int BSHIFT = 7;
constexpr int BSIZE = 128;                       // nodes per bucket
constexpr int NBKT = (N + BSIZE - 1) / BSIZE;    // 782

constexpr float FIX_SCALE = 16777216.0f;         // 2^24

constexpr int HIST_EPB = 4096;                   // edges per block, hist
constexpr int SC_EPB = 4096;                     // edges per block, scatter

__device__ __forceinline__ float ldf(const void* p, int isbf, size_t i) {
    return isbf ? __bfloat162float(((const __hip_bfloat16*)p)[i])
                : ((const float*)p)[i];
}

__device__ __forceinline__ int ld_idx(const void* ei, int is64, size_t pos) {
    return is64 ? (int)((const long long*)ei)[pos] : ((const int*)ei)[pos];
}

// --- bf16x4 pack/unpack (manual RNE, no API dependence) ---
__device__ __forceinline__ float4 bf4tof4(uint2 u) {
    float4 r;
    r.x = __uint_as_float(u.x << 16);
    r.y = __uint_as_float(u.x & 0xffff0000u);
    r.z = __uint_as_float(u.y << 16);
    r.w = __uint_as_float(u.y & 0xffff0000u);
    return r;
}
__device__ __forceinline__ unsigned short f2bf(float f) {
    unsigned u = __float_as_uint(f);
    unsigned rnd = 0x7fffu + ((u >> 16) & 1u);
    return (unsigned short)((u + rnd) >> 16);
}
__device__ __forceinline__ unsigned packbf2(float a, float b) {
    return (unsigned)f2bf(a) | ((unsigned)f2bf(b) << 16);
}
__device__ __forceinline__ uint2 f4tobf4(float4 v) {
    uint2 r;
    r.x = packbf2(v.x, v.y);
    r.y = packbf2(v.z, v.w);
    return r;
}

// flags[0] = is64 (edge_index), flags[1] = isbf (float tensors)
// also zeroes the bucket-count array (runs before k_hist on the stream)
__global__ void k_probe(const void* ei, const void* x, int* flags, int* bkt_cnt) {
    __shared__ int bad64, bigcnt;
    int t = threadIdx.x;
    if (t == 0) { bad64 = 0; bigcnt = 0; }
    __syncthreads();
    long long v = ((const long long*)ei)[t];
    if (v < 0 || v >= (long long)N) atomicAdd(&bad64, 1);
    const unsigned short* u = (const unsigned short*)x;
    int big = 0;
    for (int i = t * 16; i < t * 16 + 16; i++) {
        int e = (u[i] >> 7) & 0xFF;
        if (e >= 133) big++;
    }
    atomicAdd(&bigcnt, big);
    for (int i = t; i < NBKT; i += 256) bkt_cnt[i] = 0;
    __syncthreads();
    if (t == 0) { flags[0] = (bad64 == 0) ? 1 : 0; flags[1] = (bigcnt < 40) ? 1 : 0; }
}

// bucket histogram: batch-load targets into registers, then LDS atomics,
// one global atomic per (block,bucket)
__global__ __launch_bounds__(512) void k_hist(const void* ei, const int* flags,
                                              int* bkt_cnt) {
    constexpr int EPT = HIST_EPB / 512;          // 8
    __shared__ int h[NBKT];
    int t = threadIdx.x;
    for (int i = t; i < NBKT; i += 512) h[i] = 0;
    __syncthreads();
    int is64 = flags[0];
    size_t eb = (size_t)blockIdx.x * HIST_EPB;
    int nb = (int)min((size_t)HIST_EPB, (size_t)E - eb);
    int cc[EPT];
#pragma unroll
    for (int k = 0; k < EPT; k++) {
        int idx = t + k * 512;
        cc[k] = (idx < nb) ? ld_idx(ei, is64, (size_t)E + eb + idx) : -1;
    }
#pragma unroll
    for (int k = 0; k < EPT; k++)
        if (cc[k] >= 0) atomicAdd(&h[cc[k] >> BSHIFT], 1);
    __syncthreads();
    for (int i = t; i < NBKT; i += 512) {
        int v = h[i];
        if (v) atomicAdd(&bkt_cnt[i], v);
    }
}

// single-block exclusive scan over NBKT buckets -> bkt_off, bkt_cur
__global__ void k_bscan(const int* bkt_cnt, int* bkt_off, int* bkt_cur) {
    __shared__ int s[256];
    int t = threadIdx.x;
    int v[4]; int sum = 0;
#pragma unroll
    for (int j = 0; j < 4; j++) {
        int i = t * 4 + j;
        v[j] = (i < NBKT) ? bkt_cnt[i] : 0;
        sum += v[j];
    }
    s[t] = sum; __syncthreads();
    for (int st = 1; st < 256; st <<= 1) {
        int add = (t >= st) ? s[t - st] : 0;
        __syncthreads();
        s[t] += add;
        __syncthreads();
    }
    int excl = s[t] - sum;
#pragma unroll
    for (int j = 0; j < 4; j++) {
        int i = t * 4 + j;
        if (i < NBKT) { bkt_off[i] = excl; bkt_cur[i] = excl; excl += v[j]; }
    }
    if (t == 0) bkt_off[NBKT] = E;
}

// bucket-sort edges into tmp[]: batch-load (r,c,w) into registers ONCE,
// then per-block LDS histogram + run reservation + placement, all from
// registers. tmp entry: .x = r | (c&127)<<17  (r<2^17), .y = w bits
__global__ __launch_bounds__(512) void k_scatter(const void* ei, const int* flags,
                                                 const void* ew, int* bkt_cur,
                                                 int2* tmp) {
    constexpr int EPT = SC_EPB / 512;            // 8
    __shared__ int h[NBKT];
    __shared__ int base_s[NBKT];
    int t = threadIdx.x;
    for (int i = t; i < NBKT; i += 512) h[i] = 0;
    __syncthreads();
    int is64 = flags[0], isbf = flags[1];
    size_t eb = (size_t)blockIdx.x * SC_EPB;
    int nb = (int)min((size_t)SC_EPB, (size_t)E - eb);
    int rr[EPT], cc[EPT]; float ww[EPT];
    // batched, coalesced, independent loads; single drain
#pragma unroll
    for (int k = 0; k < EPT; k++) {
        int idx = t + k * 512;
        if (idx < nb) {
            size_t e = eb + idx;
            rr[k] = ld_idx(ei, is64, e);
            cc[k] = ld_idx(ei, is64, (size_t)E + e);
            ww[k] = ldf(ew, isbf, e);
        } else {
            rr[k] = 0; cc[k] = -1; ww[k] = 0.f;
        }
    }
    // pass 1: local histogram (registers -> LDS atomics, pipelined)
#pragma unroll
    for (int k = 0; k < EPT; k++)
        if (cc[k] >= 0) atomicAdd(&h[cc[k] >> BSHIFT], 1);
    __syncthreads();
    // reserve a dense run per bucket
    for (int i = t; i < NBKT; i += 512) {
        int v = h[i];
        base_s[i] = v ? atomicAdd(&bkt_cur[i], v) : 0;
    }
    __syncthreads();
    for (int i = t; i < NBKT; i += 512) h[i] = 0;
    __syncthreads();
    // pass 2: place edges within reserved runs (registers -> global)
#pragma unroll
    for (int k = 0; k < EPT; k++) {
        if (cc[k] >= 0) {
            int b = cc[k] >> BSHIFT;
            int loc = atomicAdd(&h[b], 1);
            int pos = base_s[b] + loc;
            tmp[pos] = make_int2(rr[k] | ((cc[k] & (BSIZE - 1)) << 17),
                                 __float_as_int(ww[k]));
        }
    }
}

// per bucket: node counts + fixed-point weight sums (LDS int atomics,
// cheap at this scale), 128-wide LDS scan -> offsets;
// dinv = rsqrt(1 + wsum) (bit-identical to the original packed scheme)
__global__ __launch_bounds__(256) void k_nodecnt(const int2* __restrict__ tmp,
                                                 const int* __restrict__ bkt_off,
                                                 int* __restrict__ counts,
                                                 int* __restrict__ offsets,
                                                 float* __restrict__ dinv) {
    __shared__ int cnt_s[BSIZE];
    __shared__ unsigned int wfx_s[BSIZE];
    __shared__ int sc_s[BSIZE];
    int t = threadIdx.x;
    int b = blockIdx.x;
    if (t < BSIZE) { cnt_s[t] = 0; wfx_s[t] = 0u; }
    __syncthreads();
    int s0 = bkt_off[b], s1 = bkt_off[b + 1];
    for (int p = s0 + t; p < s1; p += 256) {
        int2 ev = tmp[p];
        int c7 = (int)(((unsigned)ev.x) >> 17);
        float w = __int_as_float(ev.y);
        atomicAdd(&cnt_s[c7], 1);
        atomicAdd(&wfx_s[c7], (unsigned)__float2uint_rn(w * FIX_SCALE));
    }
    __syncthreads();
    if (t < BSIZE) sc_s[t] = cnt_s[t];
    __syncthreads();
    for (int st = 1; st < BSIZE; st <<= 1) {
        int add = (t < BSIZE && t >= st) ? sc_s[t - st] : 0;
        __syncthreads();
        if (t < BSIZE) sc_s[t] += add;
        __syncthreads();
    }
    if (t < BSIZE) {
        int node = b * BSIZE + t;
        if (node < N) {
            int c = cnt_s[t];
            offsets[node] = s0 + sc_s[t] - c;   // bucket base + exclusive
            counts[node] = c;
            float deg = 1.0f + (float)wfx_s[t] * (1.0f / FIX_SCALE);
            dinv[node] = rsqrtf(deg);
        }
    }
}

// per bucket: fill CSR epk[pos] = (src, dinv[src]*ew). Destination range
// is the bucket's contiguous ~32KB slice of epk -> block-private, dense.
__global__ __launch_bounds__(256) void k_fill2(const int2* __restrict__ tmp,
                                               const int* __restrict__ bkt_off,
                                               const int* __restrict__ offsets,
                                               const float* __restrict__ dinv,
                                               int2* __restrict__ epk) {
    __shared__ int lcur[BSIZE];
    int t = threadIdx.x;
    int b = blockIdx.x;
    if (t < BSIZE) {
        int node = b * BSIZE + t;
        lcur[t] = (node < N) ? offsets[node] : 0;
    }
    __syncthreads();
    int s0 = bkt_off[b], s1 = bkt_off[b + 1];
    for (int p = s0 + t; p < s1; p += 256) {
        int2 ev = tmp[p];
        unsigned px = (unsigned)ev.x;
        int r = (int)(px & 0x1FFFFu);
        int c7 = (int)(px >> 17);
        float w = __int_as_float(ev.y);
        float nr = dinv[r] * w;
        int pos = atomicAdd(&lcur[c7], 1);
        epk[pos] = make_int2(r, __float_as_int(nr));
    }
}

// --- register-blocked GEMM: H[N,FOUT] = X[N,FIN] @ W[FIN,FOUT] (+b, ELU)
// XMODE: 1 = external input (runtime fp32/bf16 probe), 2 = internal bf16.
// OBF: write bf16 (internal buffer) vs fp32 (final output).
template <int FIN, int FOUT, int TM, int TN, int XMODE, bool OBF, bool BIAS, bool ELU>
__global__ __launch_bounds__(256) void k_gemm(const void* __restrict__ X,
                                              const void* __restrict__ W,
                                              const void* __restrict__ bias,
                                              const int* __restrict__ flags,
                                              void* __restrict__ H) {
    constexpr int TCOLS = FOUT / TN;
    constexpr int TROWS = 256 / TCOLS;
    constexpr int BR = TROWS * TM;
    __shared__ float wl[FIN * FOUT];
    __shared__ float xt[FIN][BR + 1];
    int t = threadIdx.x;
    int isbf = flags[1];
    int base = blockIdx.x * BR;

    if (!isbf) {
        const float4* W4 = (const float4*)W;
        float4* wl4 = (float4*)wl;
        for (int i = t; i < FIN * FOUT / 4; i += 256) wl4[i] = W4[i];
    } else {
        for (int i = t; i < FIN * FOUT; i += 256)
            wl[i] = __bfloat162float(((const __hip_bfloat16*)W)[i]);
    }
    if (XMODE == 2) {
        // internal bf16 buffer: uint2 = 4 bf16
        const uint2* X2 = (const uint2*)X;
        for (int i = t; i < BR * FIN / 4; i += 256) {
            int row = i / (FIN / 4);
            int kq = i % (FIN / 4);
            int node = base + row;
            uint2 u = make_uint2(0u, 0u);
            if (node < N) u = X2[(size_t)node * (FIN / 4) + kq];
            float4 v = bf4tof4(u);
            int k = kq * 4;
            xt[k][row] = v.x; xt[k + 1][row] = v.y;
            xt[k + 2][row] = v.z; xt[k + 3][row] = v.w;
        }
    } else if (!isbf) {
        const float4* X4 = (const float4*)X;
        for (int i = t; i < BR * FIN / 4; i += 256) {
            int row = i / (FIN / 4);
            int kq = i % (FIN / 4);
            int node = base + row;
            float4 v = make_float4(0.f, 0.f, 0.f, 0.f);
            if (node < N) v = X4[(size_t)node * (FIN / 4) + kq];
            int k = kq * 4;
            xt[k][row] = v.x; xt[k + 1][row] = v.y;
            xt[k + 2][row] = v.z; xt[k + 3][row] = v.w;
        }
    } else {
        for (int i = t; i < BR * FIN; i += 256) {
            int row = i / FIN, k = i % FIN;
            int node = base + row;
            float v = (node < N)
                ? __bfloat162float(((const __hip_bfloat16*)X)[(size_t)node * FIN + k]) : 0.f;
            xt[k][row] = v;
        }
    }
    __syncthreads();

    int tcol = t % TCOLS, trow = t / TCOLS;
    int r0 = trow * TM, c0 = tcol * TN;
    float acc[TM][TN] = {};
#pragma unroll 4
    for (int k = 0; k < FIN; k++) {
        float a[TM], b[TN];
#pragma unroll
        for (int m = 0; m < TM; m++) a[m] = xt[k][r0 + m];
#pragma unroll
        for (int n = 0; n < TN; n++) b[n] = wl[k * FOUT + c0 + n];
#pragma unroll
        for (int m = 0; m < TM; m++)
#pragma unroll
            for (int n = 0; n < TN; n++) acc[m][n] += a[m] * b[n];
    }
#pragma unroll
    for (int m = 0; m < TM; m++) {
        int node = base + r0 + m;
        if (node >= N) continue;
        float vv[TN];
#pragma unroll
        for (int n = 0; n < TN; n++) {
            float v = acc[m][n];
            if (BIAS) v += ldf(bias, isbf, c0 + n);
            if (ELU) v = (v > 0.0f) ? v : expm1f(v);
            vv[n] = v;
        }
        if (OBF) {
            unsigned* Hrow = (unsigned*)((unsigned short*)H + (size_t)node * FOUT + c0);
#pragma unroll
            for (int n = 0; n < TN; n += 2)
                Hrow[n / 2] = packbf2(vv[n], vv[n + 1]);
        } else {
            float* Hrow = (float*)H + (size_t)node * FOUT + c0;
#pragma unroll
            for (int n = 0; n < TN; n++) Hrow[n] = vv[n];
        }
    }
}

// --- aggregation: out[n] = di*Σ_e w'_e*H[src_e] + di^2*H[n] (+b, ELU)
// (w' = dinv[src]*ew stored in CSR; dinv[target]=di applied here once)
// Node-parallel, LPN lanes per node, bf16 feature rows (uint2 = 4 bf16
// per lane). Unroll 8 + software pipeline (next 8 epk entries load
// before current gathers are accumulated). fp32 accumulation.
template <int F, bool BIAS, bool ELU>
__global__ __launch_bounds__(256) void k_agg(const uint2* __restrict__ Hb,
                                             const int* __restrict__ offsets,
                                             const int* __restrict__ counts,
                                             const int2* __restrict__ epk,
                                             const float* __restrict__ dinv,
                                             const void* __restrict__ bias,
                                             const int* __restrict__ flags,
                                             uint2* __restrict__ outb) {
    constexpr int LPN = F / 4;        // lanes per node (uint2 per lane)
    constexpr int NPB = 256 / LPN;    // nodes per block
    int t = threadIdx.x;
    int lane = t % LPN;
    int g = t / LPN;
    int node = blockIdx.x * NPB + g;
    if (node >= N) return;
    float di = dinv[node];
    float4 h = bf4tof4(Hb[(size_t)node * LPN + lane]);
    float4 acc0 = make_float4(0.f, 0.f, 0.f, 0.f);
    float4 acc1 = make_float4(0.f, 0.f, 0.f, 0.f);
    int p = offsets[node];
    int pend = p + counts[node];

    int2 eA[8];
    bool have = (p + 8 <= pend);
    if (have) {
#pragma unroll
        for (int j = 0; j < 8; j++) eA[j] = epk[p + j];
    }
    while (have) {
        // issue 8 independent gathers (8B each)
        uint2 gg[8];
#pragma unroll
        for (int j = 0; j < 8; j++)
            gg[j] = Hb[(size_t)eA[j].x * LPN + lane];
        float w[8];
#pragma unroll
        for (int j = 0; j < 8; j++) w[j] = __int_as_float(eA[j].y);
        p += 8;
        bool nxt = (p + 8 <= pend);
        int2 eB[8];
        if (nxt) {
#pragma unroll
            for (int j = 0; j < 8; j++) eB[j] = epk[p + j];
        }
        // accumulate current batch (drains gather vmcnt; next epk loads
        // already in flight)
#pragma unroll
        for (int j = 0; j < 8; j += 2) {
            float4 g0 = bf4tof4(gg[j]);
            float4 g1 = bf4tof4(gg[j + 1]);
            acc0.x += g0.x * w[j]; acc0.y += g0.y * w[j];
            acc0.z += g0.z * w[j]; acc0.w += g0.w * w[j];
            acc1.x += g1.x * w[j + 1]; acc1.y += g1.y * w[j + 1];
            acc1.z += g1.z * w[j + 1]; acc1.w += g1.w * w[j + 1];
        }
#pragma unroll
        for (int j = 0; j < 8; j++) eA[j] = eB[j];
        have = nxt;
    }
    // tail: 4-wide then scalar
    for (; p + 4 <= pend; p += 4) {
        int2 e0 = epk[p], e1 = epk[p + 1], e2 = epk[p + 2], e3 = epk[p + 3];
        float4 h0 = bf4tof4(Hb[(size_t)e0.x * LPN + lane]);
        float4 h1 = bf4tof4(Hb[(size_t)e1.x * LPN + lane]);
        float4 h2 = bf4tof4(Hb[(size_t)e2.x * LPN + lane]);
        float4 h3 = bf4tof4(Hb[(size_t)e3.x * LPN + lane]);
        float w0 = __int_as_float(e0.y), w1 = __int_as_float(e1.y);
        float w2 = __int_as_float(e2.y), w3 = __int_as_float(e3.y);
        acc0.x += h0.x * w0 + h2.x * w2; acc1.x += h1.x * w1 + h3.x * w3;
        acc0.y += h0.y * w0 + h2.y * w2; acc1.y += h1.y * w1 + h3.y * w3;
        acc0.z += h0.z * w0 + h2.z * w2; acc1.z += h1.z * w1 + h3.z * w3;
        acc0.w += h0.w * w0 + h2.w * w2; acc1.w += h1.w * w1 + h3.w * w3;
    }
    for (; p < pend; p++) {
        int2 e = epk[p];
        float4 hh = bf4tof4(Hb[(size_t)e.x * LPN + lane]);
        float w = __int_as_float(e.y);
        acc0.x += hh.x * w; acc0.y += hh.y * w;
        acc0.z += hh.z * w; acc0.w += hh.w * w;
    }
    float4 acc;
    acc.x = acc0.x + acc1.x; acc.y = acc0.y + acc1.y;
    acc.z = acc0.z + acc1.z; acc.w = acc0.w + acc1.w;
    float sw = di * di;
    acc.x = acc.x * di + h.x * sw;
    acc.y = acc.y * di + h.y * sw;
    acc.z = acc.z * di + h.z * sw;
    acc.w = acc.w * di + h.w * sw;
    if (BIAS) {
        int fb = lane * 4;
        int isbf = flags[1];
        acc.x += ldf(bias, isbf, fb);
        acc.y += ldf(bias, isbf, fb + 1);
        acc.z += ldf(bias, isbf, fb + 2);
        acc.w += ldf(bias, isbf, fb + 3);
    }
    if (ELU) {
        acc.x = (acc.x > 0.0f) ? acc.x : expm1f(acc.x);
        acc.y = (acc.y > 0.0f) ? acc.y : expm1f(acc.y);
        acc.z = (acc.z > 0.0f) ? acc.z : expm1f(acc.z);
        acc.w = (acc.w > 0.0f) ? acc.w : expm1f(acc.w);
    }
    outb[(size_t)node * LPN + lane] = f4tobf4(acc);
}

// diagnostic fallback: if ws_size too small, emit sentinel 123.0
__global__ void k_sentinel(float* out, int n) {
    int i = blockIdx.x * blockDim.x + threadIdx.x;
    if (i < n) out[i] = 123.0f;
}

extern "C" void kernel_launch(void* const* d_in, const int* in_sizes, int n_in,
                              void* d_out, int out_size, void* d_ws, size_t ws_size,
                              hipStream_t stream) {
    const void* x  = d_in[0];
    const void* ei = d_in[1];
    const void* ea = d_in[2];
    const void* W1 = d_in[3];
    const void* b1 = d_in[4];
    const void* W2 = d_in[5];
    const void* b2 = d_in[6];
    const void* W3 = d_in[7];
    const void* b3 = d_in[8];
    float* out = (float*)d_out;

    // workspace layout (256B aligned)
    char* ws = (char*)d_ws;
    size_t off = 0;
    auto alloc = [&](size_t bytes) {
        off = (off + 255) & ~(size_t)255;
        size_t r = off;
        off += bytes;
        return r;
    };
    float* dinv    = (float*)(ws + alloc((size_t)N * 4));
    int*   counts  = (int*)  (ws + alloc((size_t)N * 4));
    int*   offsets = (int*)  (ws + alloc((size_t)N * 4));
    int*   bkt_cnt = (int*)  (ws + alloc((size_t)NBKT * 4));
    int*   bkt_off = (int*)  (ws + alloc((size_t)(NBKT + 1) * 4));
    int*   bkt_cur = (int*)  (ws + alloc((size_t)NBKT * 4));
    int*   flags   = (int*)  (ws + alloc(256));
    int2*  epk     = (int2*) (ws + alloc((size_t)E * 8));
    // bf16 feature buffers: N*64*2 = 12.8MB each; allocated back-to-back
    // (12.8MB is 256B-aligned) so tmp (E*8 = 25.6MB) aliases bufA+bufB.
    // tmp's last read (k_fill2) precedes bufA's first write (L1 GEMM).
    unsigned short* bufA = (unsigned short*)(ws + alloc((size_t)N * 64 * 2));
    unsigned short* bufB = (unsigned short*)(ws + alloc((size_t)N * 64 * 2));
    size_t need = off;
    int2* tmp = (int2*)bufA;

    if (ws_size < need) {
        hipLaunchKernelGGL(k_sentinel, dim3((N * 128 + 255) / 256), dim3(256), 0, stream,
                           out, N * 128);
        return;
    }

    const int gH = (E + HIST_EPB - 1) / HIST_EPB;   // 782
    const int gS = (E + SC_EPB - 1) / SC_EPB;       // 782

    hipLaunchKernelGGL(k_probe, dim3(1), dim3(256), 0, stream, ei, x, flags, bkt_cnt);
    hipLaunchKernelGGL(k_hist, dim3(gH), dim3(512), 0, stream, ei, flags, bkt_cnt);
    hipLaunchKernelGGL(k_bscan, dim3(1), dim3(256), 0, stream, bkt_cnt, bkt_off, bkt_cur);
    hipLaunchKernelGGL(k_scatter, dim3(gS), dim3(512), 0, stream, ei, flags, ea, bkt_cur, tmp);
    hipLaunchKernelGGL(k_nodecnt, dim3(NBKT), dim3(256), 0, stream, tmp, bkt_off,
                       counts, offsets, dinv);
    hipLaunchKernelGGL(k_fill2, dim3(NBKT), dim3(256), 0, stream, tmp, bkt_off,
                       offsets, dinv, epk);

    // L1: t1 = x@W1 (bufA, F=32 bf16); a1 = ELU(agg(t1)+b1) (bufB bf16)
    hipLaunchKernelGGL((k_gemm<128, 32, 2, 4, 1, true, false, false>),
                       dim3((N + 63) / 64), dim3(256), 0, stream, x, W1, nullptr, flags, bufA);
    hipLaunchKernelGGL((k_agg<32, true, true>), dim3((N + 31) / 32), dim3(256), 0, stream,
                       (const uint2*)bufA, offsets, counts, epk, dinv, b1, flags, (uint2*)bufB);
    // L2: s2 = agg(a1) (bufA bf16); h2 = ELU(s2@W2+b2) (bufB, F=64 bf16)
    hipLaunchKernelGGL((k_agg<32, false, false>), dim3((N + 31) / 32), dim3(256), 0, stream,
                       (const uint2*)bufB, offsets, counts, epk, dinv, nullptr, flags, (uint2*)bufA);
    hipLaunchKernelGGL((k_gemm<32, 64, 4, 4, 2, true, true, true>),
                       dim3((N + 63) / 64), dim3(256), 0, stream, bufA, W2, b2, flags, bufB);
    // L3: s3 = agg(h2) (bufA, F=64 bf16); out = s3@W3+b3 (d_out fp32)
    hipLaunchKernelGGL((k_agg<64, false, false>), dim3((N + 15) / 16), dim3(256), 0, stream,
                       (const uint2*)bufB, offsets, counts, epk, dinv, nullptr, flags, (uint2*)bufA);
    hipLaunchKernelGGL((k_gemm<64, 128, 4, 8, 2, false, true, false>),
                       dim3((N + 63) / 64), dim3(256), 0, stream, bufA, W3, b3, flags, out);
}